// Round 4
// baseline (6945.535 us; speedup 1.0000x reference)
//
#include <hip/hip_runtime.h>
#include <hip/hip_cooperative_groups.h>
#include <math.h>

namespace cg = cooperative_groups;

// Sizes fixed by the problem.
#define B_TOT 131072
#define M_N   1024
#define BS    128      // Cholesky block size
#define NBK   8        // M_N / BS

typedef float  f32x4  __attribute__((ext_vector_type(4)));
typedef short  bf16x8 __attribute__((ext_vector_type(8)));

// Workspace layout (bytes). Total ~20.2 MB.
enum : size_t {
    OFF_K  = 0,                          // fp64 K / L           8 MB
    OFF_W  = (size_t)8 << 20,            // fp64 W = L^-1        8 MB
    OFF_PD = (size_t)16 << 20,           // fp64 params (6)
    OFF_PF = ((size_t)16 << 20) + 256,   // fp32 params (6)
    OFF_ZD = ((size_t)16 << 20) + 512,   // fp64 Zs [1024][5]    40960
    OFF_ZT = OFF_ZD + (size_t)M_N * 5 * 8,   // fp32 Zs_t [5][1024]  20480
    OFF_WPH = OFF_ZT + (size_t)M_N * 5 * 4,  // bf16 W packed hi     2 MB
    OFF_WPL = OFF_WPH + (size_t)M_N * M_N * 2,  // bf16 W packed lo  2 MB
};

__device__ __constant__ double c_zscale[5] = {0.15, 0.1, 0.05, 800.0, 20.0};
__device__ __constant__ double c_zshift[5] = {0.0, 0.0, 0.0, 600.0, 5.0};

static __device__ __forceinline__ unsigned short f2bf(float f) {
    unsigned u = __float_as_uint(f);
    unsigned r = (u + 0x7fff + ((u >> 16) & 1)) >> 16;   // RNE
    return (unsigned short)r;
}
static __device__ __forceinline__ float bf2f(unsigned short s) {
    return __uint_as_float(((unsigned)s) << 16);
}

// ================= device-side phases (shared by cooperative + fallback) =================

static __device__ void d_params(const float* log_ls, const float* log_var,
                                double* pd, float* pf, int tid) {
    if (tid < 5) {
        double ls  = exp((double)log_ls[tid]);
        double inv = 1.0 / (ls + 1e-8);
        pd[tid] = inv; pf[tid] = (float)inv;
    }
    if (tid == 5) {
        double pv = exp((double)log_var[0]);
        pd[5] = pv; pf[5] = (float)pv;
    }
}

static __device__ void d_prepz(const float* Zraw, const double* pd,
                               double* Zsd, float* Zst, int gtid, int gstride) {
    for (int m = gtid; m < M_N; m += gstride) {
#pragma unroll
        for (int d = 0; d < 5; ++d) {
            double z  = (double)Zraw[m * 5 + d] * c_zscale[d] + c_zshift[d];
            double zs = z * pd[d];
            Zsd[m * 5 + d]   = zs;
            Zst[d * M_N + m] = (float)zs;
        }
    }
}

static __device__ void d_buildK(const double* Zsd, const double* pd,
                                double* Kd, int gtid, int gstride) {
    for (int idx = gtid; idx < M_N * M_N; idx += gstride) {
        int i = idx >> 10, j = idx & 1023;
        double d2 = 0.0;
#pragma unroll
        for (int d = 0; d < 5; ++d) {
            double df = Zsd[i * 5 + d] - Zsd[j * 5 + d];
            d2 += df * df;
        }
        double dd = d2 + 1e-8;
        double dist = sqrt(dd);
        double s = 2.2360679774997896 * dist;
        double v = pd[5] * (1.0 + s + (5.0 / 3.0) * dd) * exp(-s);
        if (i == j) v += 1e-4;
        Kd[(size_t)idx] = v;
    }
}

// Cholesky diag block (256 thr: thread-pairs per row) + W11 = inv(L11).
// smem: As[128][129] at 0, sinv[128] at 16512.  (16640 doubles)
static __device__ void d_diag(double* Kd, double* Wd, int kb, double* smem, int tid) {
    double (*As)[129] = (double(*)[129])smem;
    double* sinv = smem + 16512;
    int r0 = kb * BS;
    for (int idx = tid; idx < BS * BS; idx += 256) {
        int rr = idx >> 7, cc = idx & 127;
        As[rr][cc] = Kd[(size_t)(r0 + rr) * M_N + r0 + cc];
    }
    __syncthreads();

    int r = tid & 127;
    int half = tid >> 7;
    for (int p = 0; p < 16; ++p) {
        int j0 = p * 8;
        for (int j = j0; j < j0 + 8; ++j) {
            if (r == j && half == 0) {
                double d = sqrt(As[j][j]);
                As[j][j] = d;
                sinv[j] = 1.0 / d;
            }
            __syncthreads();
            double arj = 0.0;
            if (r > j && half == 0) {
                arj = As[r][j] * sinv[j];
                As[r][j] = arj;
            }
            __syncthreads();
            if (r > j && half == 0) {
                for (int c = j + 1; c < j0 + 8; ++c)
                    As[r][c] -= arj * As[c][j];
            }
        }
        __syncthreads();
        // rank-8 trailing update; both halves split the column range
        if (r >= j0 + 8) {
            double a[8];
#pragma unroll
            for (int t = 0; t < 8; ++t) a[t] = As[r][j0 + t];
            for (int c = j0 + 8 + half; c <= r; c += 2) {
                double s = As[r][c];
#pragma unroll
                for (int t = 0; t < 8; ++t) s -= a[t] * As[c][j0 + t];
                As[r][c] = s;
            }
        }
        __syncthreads();
    }

    // W11 = inv(L11): thread c (<128) owns column c; X[t][c] stored at As[c][t] (t>c)
    if (tid < 128) {
        int c = tid;
        for (int rb = 0; rb < 16; ++rb) {
            int r0b = rb * 8;
            if (c >= r0b + 8) continue;
            double s[8];
#pragma unroll
            for (int i = 0; i < 8; ++i) s[i] = 0.0;
            for (int t = 0; t < r0b; ++t) {
                if (t >= c) {
                    double xt = (t == c) ? sinv[c] : As[c][t];
#pragma unroll
                    for (int i = 0; i < 8; ++i) s[i] += As[r0b + i][t] * xt;
                }
            }
            double xloc[8];
#pragma unroll
            for (int i = 0; i < 8; ++i) {
                int rr = r0b + i;
                double v = 0.0;
                if (rr >= c) {
                    v = ((rr == c) ? 1.0 : 0.0) - s[i];
#pragma unroll
                    for (int t2 = 0; t2 < i; ++t2) {
                        int tt = r0b + t2;
                        if (tt >= c) v -= As[rr][tt] * xloc[t2];
                    }
                    v *= sinv[rr];
                    if (rr > c) As[c][rr] = v;
                }
                xloc[i] = v;
            }
        }
    }
    __syncthreads();
    for (int idx = tid; idx < BS * BS; idx += 256) {
        int rr = idx >> 7, cc = idx & 127;
        if (rr >= cc)
            Wd[(size_t)(r0 + rr) * M_N + r0 + cc] = (rr == cc) ? sinv[rr] : As[cc][rr];
    }
    __syncthreads();
}

// panel: L21 strip (64 rows) = A21 * W11^T.  smem: As[64][16] at 0, Ws[16][128] at 1024.
static __device__ void d_panel(double* Kd, const double* Wd, int kb, int vb,
                               double* smem, int tid) {
    double (*As)[16]  = (double(*)[16])smem;
    double (*Ws)[128] = (double(*)[128])(smem + 1024);
    int row0 = (kb + 1) * BS + vb * 64;
    int cb = kb * BS;
    int c = tid & 127, q = tid >> 7;
    double acc[32];
#pragma unroll
    for (int i = 0; i < 32; ++i) acc[i] = 0.0;
    for (int tc = 0; tc < 8; ++tc) {
        int tb = tc * 16;
        for (int idx = tid; idx < 64 * 16; idx += 256) {
            int rr = idx >> 4, tt = idx & 15;
            As[rr][tt] = Kd[(size_t)(row0 + rr) * M_N + cb + tb + tt];
        }
        for (int idx = tid; idx < 128 * 16; idx += 256) {
            int cc = idx >> 4, tt = idx & 15;
            Ws[tt][cc] = (tb + tt <= cc) ? Wd[(size_t)(cb + cc) * M_N + cb + tb + tt] : 0.0;
        }
        __syncthreads();
#pragma unroll
        for (int t = 0; t < 16; ++t) {
            double w = Ws[t][c];
#pragma unroll
            for (int i = 0; i < 32; ++i) acc[i] += As[q * 32 + i][t] * w;
        }
        __syncthreads();
    }
#pragma unroll
    for (int i = 0; i < 32; ++i)
        Kd[(size_t)(row0 + q * 32 + i) * M_N + cb + c] = acc[i];
    __syncthreads();
}

// trailing update tile (by,bx) lower: A22 -= L21 L21^T. smem: As2[64][17], Bs2[64][17].
static __device__ void d_update(double* Kd, int kb, int by, int bx,
                                double* smem, int tid) {
    double (*As2)[17] = (double(*)[17])smem;
    double (*Bs2)[17] = (double(*)[17])(smem + 64 * 17);
    int base = (kb + 1) * BS;
    int gr0 = base + by * 64;
    int gc0 = base + bx * 64;
    int cb = kb * BS;
    int tx = tid & 15, ty = tid >> 4;
    double acc[4][4];
#pragma unroll
    for (int i = 0; i < 4; ++i)
#pragma unroll
        for (int j = 0; j < 4; ++j) acc[i][j] = 0.0;
    for (int tc = 0; tc < 8; ++tc) {
        int tb = tc * 16;
        for (int idx = tid; idx < 1024; idx += 256) {
            int rr = idx >> 4, tt = idx & 15;
            As2[rr][tt] = Kd[(size_t)(gr0 + rr) * M_N + cb + tb + tt];
            Bs2[rr][tt] = Kd[(size_t)(gc0 + rr) * M_N + cb + tb + tt];
        }
        __syncthreads();
#pragma unroll
        for (int t = 0; t < 16; ++t) {
            double a[4], b[4];
#pragma unroll
            for (int i = 0; i < 4; ++i) a[i] = As2[ty * 4 + i][t];
#pragma unroll
            for (int j = 0; j < 4; ++j) b[j] = Bs2[tx * 4 + j][t];
#pragma unroll
            for (int i = 0; i < 4; ++i)
#pragma unroll
                for (int j = 0; j < 4; ++j) acc[i][j] += a[i] * b[j];
        }
        __syncthreads();
    }
#pragma unroll
    for (int i = 0; i < 4; ++i)
#pragma unroll
        for (int j = 0; j < 4; ++j)
            Kd[(size_t)(gr0 + ty * 4 + i) * M_N + gc0 + tx * 4 + j] -= acc[i][j];
    __syncthreads();
}

// trtri off-diag block (i=j+dd, col-tile ct). smem: Ls[128][33], Ws2[32][65], Ps[128][65].
static __device__ void d_trtri(const double* Kd, double* Wd, int dd, int j, int ct,
                               double* smem, int tid) {
    double (*Ls)[33]  = (double(*)[33])smem;               // 4224
    double (*Ws2)[65] = (double(*)[65])(smem + 4224);      // 2080
    double (*Ps)[65]  = (double(*)[65])(smem + 6304);      // 8320
    int i = j + dd;
    int i0 = i * BS, j0 = j * BS, c0 = j0 + ct * 64;
    int rq = tid >> 3, cq = tid & 7;
    double acc[4][8];
#pragma unroll
    for (int k = 0; k < 4; ++k)
#pragma unroll
        for (int c = 0; c < 8; ++c) acc[k][c] = 0.0;

    for (int tb = j; tb < i; ++tb) {
        for (int ch = 0; ch < 4; ++ch) {
            int tbase = tb * BS + ch * 32;
            for (int idx = tid; idx < 128 * 32; idx += 256) {
                int rr = idx >> 5, tt = idx & 31;
                Ls[rr][tt] = Kd[(size_t)(i0 + rr) * M_N + tbase + tt];
            }
            for (int idx = tid; idx < 32 * 64; idx += 256) {
                int tt = idx >> 6, cc = idx & 63;
                int gr = tbase + tt, gc = c0 + cc;
                Ws2[tt][cc] = (tb == j && gr < gc) ? 0.0 : Wd[(size_t)gr * M_N + gc];
            }
            __syncthreads();
#pragma unroll
            for (int tt = 0; tt < 32; ++tt) {
                double l_[4];
#pragma unroll
                for (int k = 0; k < 4; ++k) l_[k] = Ls[rq + 32 * k][tt];
#pragma unroll
                for (int k = 0; k < 4; ++k)
#pragma unroll
                    for (int c = 0; c < 8; ++c)
                        acc[k][c] += l_[k] * Ws2[tt][cq * 8 + c];
            }
            __syncthreads();
        }
    }
#pragma unroll
    for (int k = 0; k < 4; ++k)
#pragma unroll
        for (int c = 0; c < 8; ++c) Ps[rq + 32 * k][cq * 8 + c] = acc[k][c];
    __syncthreads();

    double a2[4][8];
#pragma unroll
    for (int k = 0; k < 4; ++k)
#pragma unroll
        for (int c = 0; c < 8; ++c) a2[k][c] = 0.0;
    for (int ch = 0; ch < 4; ++ch) {
        for (int idx = tid; idx < 128 * 32; idx += 256) {
            int rr = idx >> 5, tt = idx & 31;
            int col = ch * 32 + tt;
            Ls[rr][tt] = (col <= rr) ? Wd[(size_t)(i0 + rr) * M_N + i0 + col] : 0.0;
        }
        __syncthreads();
#pragma unroll
        for (int tt = 0; tt < 32; ++tt) {
            double l_[4];
#pragma unroll
            for (int k = 0; k < 4; ++k) l_[k] = Ls[rq + 32 * k][tt];
#pragma unroll
            for (int k = 0; k < 4; ++k)
#pragma unroll
                for (int c = 0; c < 8; ++c)
                    a2[k][c] += l_[k] * Ps[ch * 32 + tt][cq * 8 + c];
        }
        __syncthreads();
    }
#pragma unroll
    for (int k = 0; k < 4; ++k)
#pragma unroll
        for (int c = 0; c < 8; ++c)
            Wd[(size_t)(i0 + rq + 32 * k) * M_N + c0 + cq * 8 + c] = -a2[k][c];
    __syncthreads();
}

// pack W into MFMA B-fragment order, bf16 hi/lo.
static __device__ void d_pack(const double* Wd, short* Wph, short* Wpl,
                              int gtid, int gstride) {
    for (int T = gtid; T < M_N * M_N / 8; T += gstride) {
        int lane = T & 63, fid = T >> 6;
        int jn = fid & 63, kik = fid >> 6;
        int ki = kik & 3, kc = kik >> 2;
        int j  = jn * 16 + (lane & 15);
        int kb = kc * 128 + ki * 32 + (lane >> 4) * 8;
        bf16x8 h, lo;
#pragma unroll
        for (int e = 0; e < 8; ++e) {
            int k = kb + e;
            float v = (k <= j) ? (float)Wd[(size_t)j * M_N + k] : 0.0f;
            unsigned short hb = f2bf(v);
            h[e]  = (short)hb;
            lo[e] = (short)f2bf(v - bf2f(hb));
        }
        size_t off = (size_t)fid * 512 + lane * 8;
        *(bf16x8*)(Wph + off) = h;
        *(bf16x8*)(Wpl + off) = lo;
    }
}

// ================= cooperative mega-kernel: whole factorization pipeline =================
__global__ __launch_bounds__(256, 1) void k_factor(const float* log_ls, const float* log_var,
                                                   const float* Zraw,
                                                   double* Kd, double* Wd,
                                                   double* pd, float* pf,
                                                   double* Zsd, float* Zst,
                                                   short* Wph, short* Wpl) {
    __shared__ double smem[16768];   // 134,144 B -> 1 block/CU
    cg::grid_group grid = cg::this_grid();
    int tid = threadIdx.x, bid = blockIdx.x, nb = gridDim.x;
    int gtid = bid * 256 + tid, gstride = nb * 256;

    if (bid == 0) d_params(log_ls, log_var, pd, pf, tid);
    grid.sync();
    d_prepz(Zraw, pd, Zsd, Zst, gtid, gstride);
    grid.sync();
    d_buildK(Zsd, pd, Kd, gtid, gstride);
    grid.sync();

    for (int kb = 0; kb < NBK; ++kb) {
        if (bid == 0) d_diag(Kd, Wd, kb, smem, tid);
        grid.sync();
        int R = M_N - (kb + 1) * BS;
        if (R > 0) {
            for (int vb = bid; vb < R / 64; vb += nb) d_panel(Kd, Wd, kb, vb, smem, tid);
            grid.sync();
            int nt = R / 64, cnt = nt * (nt + 1) / 2;
            for (int v = bid; v < cnt; v += nb) {
                int by = 0;
                while ((by + 1) * (by + 2) / 2 <= v) ++by;
                int bx = v - by * (by + 1) / 2;
                d_update(Kd, kb, by, bx, smem, tid);
            }
            grid.sync();
        }
    }

    for (int dd = 1; dd < NBK; ++dd) {
        int nvb = (NBK - dd) * 2;
        for (int vb = bid; vb < nvb; vb += nb)
            d_trtri(Kd, Wd, dd, vb >> 1, vb & 1, smem, tid);
        grid.sync();
    }

    d_pack(Wd, Wph, Wpl, gtid, gstride);
}

// ================= fallback wrappers (used only if cooperative launch fails) ============
__global__ void kw_prep(const float* a, const float* b, double* pd, float* pf) {
    d_params(a, b, pd, pf, threadIdx.x);
}
__global__ void kw_prepz(const float* Zraw, const double* pd, double* Zsd, float* Zst) {
    d_prepz(Zraw, pd, Zsd, Zst, blockIdx.x * 256 + threadIdx.x, gridDim.x * 256);
}
__global__ void kw_buildK(const double* Zsd, const double* pd, double* Kd) {
    d_buildK(Zsd, pd, Kd, blockIdx.x * 256 + threadIdx.x, gridDim.x * 256);
}
__global__ __launch_bounds__(256) void kw_diag(double* Kd, double* Wd, int kb) {
    __shared__ double s[16768];
    d_diag(Kd, Wd, kb, s, threadIdx.x);
}
__global__ __launch_bounds__(256) void kw_panel(double* Kd, const double* Wd, int kb) {
    __shared__ double s[3072];
    d_panel(Kd, Wd, kb, blockIdx.x, s, threadIdx.x);
}
__global__ __launch_bounds__(256) void kw_update(double* Kd, int kb) {
    __shared__ double s[2176];
    int v = blockIdx.x;
    int by = 0;
    while ((by + 1) * (by + 2) / 2 <= v) ++by;
    int bx = v - by * (by + 1) / 2;
    d_update(Kd, kb, by, bx, s, threadIdx.x);
}
__global__ __launch_bounds__(256) void kw_trtri(const double* Kd, double* Wd, int dd) {
    __shared__ double s[14624];
    d_trtri(Kd, Wd, dd, blockIdx.x >> 1, blockIdx.x & 1, s, threadIdx.x);
}
__global__ void kw_pack(const double* Wd, short* Wph, short* Wpl) {
    d_pack(Wd, Wph, Wpl, blockIdx.x * 256 + threadIdx.x, gridDim.x * 256);
}

// ================= main MFMA kernel: 32 rows x 1024 cols per block, dbuf LDS ============
__global__ __launch_bounds__(512, 2) void k_mm(const float* __restrict__ x_star,
                                               const float* __restrict__ pf,
                                               const float* __restrict__ Zs_t,
                                               const short* __restrict__ Wph,
                                               const short* __restrict__ Wpl,
                                               float* __restrict__ out, int Bq) {
    __shared__ __align__(16) char kls[2][2][32 * 256];  // [dbuf][hi/lo][row][256B]
    __shared__ float xs[32][5];
    __shared__ float red_l[32];
    int tid  = threadIdx.x;
    int slab = blockIdx.x;
    int w = tid >> 6, lane = tid & 63;
    int lrow = lane & 15, kgrp = lane >> 4;

    if (tid < 32) {
        int qrow = slab * 32 + tid;
        int qc = (qrow < Bq) ? qrow : (Bq - 1);
#pragma unroll
        for (int d = 0; d < 5; ++d) xs[tid][d] = x_star[(size_t)qc * 5 + d] * pf[d];
        red_l[tid] = 0.0f;
    }
    float pv = pf[5];
    __syncthreads();

    auto stage = [&](int kc, char (*buf)[32 * 256]) {
        int row = tid >> 4, cc = tid & 15;
        float x0 = xs[row][0], x1 = xs[row][1], x2 = xs[row][2],
              x3 = xs[row][3], x4 = xs[row][4];
        int lb = kc * 128 + cc * 8;
        float z0[8], z1[8], z2[8], z3[8], z4[8];
        *(float4*)&z0[0] = *(const float4*)&Zs_t[lb];
        *(float4*)&z0[4] = *(const float4*)&Zs_t[lb + 4];
        *(float4*)&z1[0] = *(const float4*)&Zs_t[M_N + lb];
        *(float4*)&z1[4] = *(const float4*)&Zs_t[M_N + lb + 4];
        *(float4*)&z2[0] = *(const float4*)&Zs_t[2 * M_N + lb];
        *(float4*)&z2[4] = *(const float4*)&Zs_t[2 * M_N + lb + 4];
        *(float4*)&z3[0] = *(const float4*)&Zs_t[3 * M_N + lb];
        *(float4*)&z3[4] = *(const float4*)&Zs_t[3 * M_N + lb + 4];
        *(float4*)&z4[0] = *(const float4*)&Zs_t[4 * M_N + lb];
        *(float4*)&z4[4] = *(const float4*)&Zs_t[4 * M_N + lb + 4];
        bf16x8 hv, lv;
#pragma unroll
        for (int e = 0; e < 8; ++e) {
            float dx0 = x0 - z0[e], dx1 = x1 - z1[e], dx2 = x2 - z2[e],
                  dx3 = x3 - z3[e], dx4 = x4 - z4[e];
            float d2 = dx0 * dx0 + dx1 * dx1 + dx2 * dx2 + dx3 * dx3 + dx4 * dx4;
            float ddv = d2 + 1e-8f;
            float dist = sqrtf(ddv);
            float sv = 2.23606798f * dist;
            float kvf = pv * (1.0f + sv + 1.66666667f * ddv) * __expf(-sv);
            unsigned short hb = f2bf(kvf);
            hv[e] = (short)hb;
            lv[e] = (short)f2bf(kvf - bf2f(hb));
        }
        int off = row * 256 + ((cc * 16) ^ ((row & 15) << 4));
        *(bf16x8*)(&buf[0][off]) = hv;
        *(bf16x8*)(&buf[1][off]) = lv;
    };

    f32x4 acc[2][8];
#pragma unroll
    for (int mi = 0; mi < 2; ++mi)
#pragma unroll
        for (int nj = 0; nj < 8; ++nj) acc[mi][nj] = (f32x4)(0.0f);

    int jmax_w = (56 + w) * 16 + 15;   // wave's max output column (jng = w + 8*nj)

    stage(0, kls[0]);
    __syncthreads();

    for (int kc = 0; kc < 8; ++kc) {
        if (kc < 7) stage(kc + 1, kls[(kc + 1) & 1]);
        char (*cur)[32 * 256] = kls[kc & 1];
        for (int ki = 0; ki < 4; ++ki) {
            int kmin = kc * 128 + ki * 32;
            if (kmin > jmax_w) break;            // wave-uniform
            bf16x8 Ah[2], Al[2];
#pragma unroll
            for (int mi = 0; mi < 2; ++mi) {
                int row = mi * 16 + lrow;
                int cb  = ki * 64 + kgrp * 16;
                int off = row * 256 + (cb ^ ((row & 15) << 4));
                Ah[mi] = *(const bf16x8*)(&cur[0][off]);
                Al[mi] = *(const bf16x8*)(&cur[1][off]);
            }
#pragma unroll
            for (int nj = 0; nj < 8; ++nj) {
                int jng = w + 8 * nj;                 // balanced col interleave
                if (kmin > jng * 16 + 15) continue;   // all-zero W fragment
                size_t fo = ((size_t)((kc * 4 + ki) * 64 + jng)) * 512 + lane * 8;
                bf16x8 Bh = *(const bf16x8*)(Wph + fo);
                bf16x8 Bl = *(const bf16x8*)(Wpl + fo);
#pragma unroll
                for (int mi = 0; mi < 2; ++mi) {
                    acc[mi][nj] = __builtin_amdgcn_mfma_f32_16x16x32_bf16(Ah[mi], Bh, acc[mi][nj], 0, 0, 0);
                    acc[mi][nj] = __builtin_amdgcn_mfma_f32_16x16x32_bf16(Ah[mi], Bl, acc[mi][nj], 0, 0, 0);
                    acc[mi][nj] = __builtin_amdgcn_mfma_f32_16x16x32_bf16(Al[mi], Bh, acc[mi][nj], 0, 0, 0);
                }
            }
        }
        __syncthreads();
    }

    // epilogue: red[row] += y^2 ; C layout: row = mi*16 + kgrp*4 + q, col = jng*16 + lrow
#pragma unroll
    for (int mi = 0; mi < 2; ++mi) {
#pragma unroll
        for (int q = 0; q < 4; ++q) {
            float s = 0.0f;
#pragma unroll
            for (int nj = 0; nj < 8; ++nj) s = fmaf(acc[mi][nj][q], acc[mi][nj][q], s);
            s += __shfl_xor(s, 1);
            s += __shfl_xor(s, 2);
            s += __shfl_xor(s, 4);
            s += __shfl_xor(s, 8);
            if (lrow == 0) atomicAdd(&red_l[mi * 16 + kgrp * 4 + q], s);
        }
    }
    __syncthreads();
    if (tid < 32) {
        int b = slab * 32 + tid;
        if (b < Bq) out[b] = sqrtf(fmaxf(pv - red_l[tid], 1e-6f));
    }
}

extern "C" void kernel_launch(void* const* d_in, const int* in_sizes, int n_in,
                              void* d_out, int out_size, void* d_ws, size_t ws_size,
                              hipStream_t stream) {
    const float* x_star  = (const float*)d_in[0];
    const float* log_ls  = (const float*)d_in[1];
    const float* log_var = (const float*)d_in[2];
    const float* Z_raw   = (const float*)d_in[3];
    float* out = (float*)d_out;
    int Bq = in_sizes[0] / 5;

    char* ws = (char*)d_ws;
    double* Kd   = (double*)(ws + OFF_K);
    double* Wd   = (double*)(ws + OFF_W);
    double* pd   = (double*)(ws + OFF_PD);
    float*  pf   = (float*)(ws + OFF_PF);
    double* Zsd  = (double*)(ws + OFF_ZD);
    float*  Zst  = (float*)(ws + OFF_ZT);
    short*  Wph  = (short*)(ws + OFF_WPH);
    short*  Wpl  = (short*)(ws + OFF_WPL);

    void* args[] = {(void*)&log_ls, (void*)&log_var, (void*)&Z_raw,
                    (void*)&Kd, (void*)&Wd, (void*)&pd, (void*)&pf,
                    (void*)&Zsd, (void*)&Zst, (void*)&Wph, (void*)&Wpl};
    hipError_t ce = hipLaunchCooperativeKernel((void*)k_factor, dim3(128), dim3(256),
                                               args, 0, stream);
    if (ce != hipSuccess) {
        // fallback: classic multi-launch chain
        kw_prep<<<1, 64, 0, stream>>>(log_ls, log_var, pd, pf);
        kw_prepz<<<4, 256, 0, stream>>>(Z_raw, pd, Zsd, Zst);
        kw_buildK<<<4096, 256, 0, stream>>>(Zsd, pd, Kd);
        for (int kb = 0; kb < NBK; ++kb) {
            kw_diag<<<1, 256, 0, stream>>>(Kd, Wd, kb);
            int R = M_N - (kb + 1) * BS;
            if (R > 0) {
                int nt = R / 64;
                kw_panel<<<nt, 256, 0, stream>>>(Kd, Wd, kb);
                kw_update<<<nt * (nt + 1) / 2, 256, 0, stream>>>(Kd, kb);
            }
        }
        for (int dd = 1; dd < NBK; ++dd)
            kw_trtri<<<(NBK - dd) * 2, 256, 0, stream>>>(Kd, Wd, dd);
        kw_pack<<<512, 256, 0, stream>>>(Wd, Wph, Wpl);
    }

    int slabs = (Bq + 31) / 32;
    k_mm<<<slabs, 512, 0, stream>>>(x_star, pf, Zst, Wph, Wpl, out, Bq);
}

// Round 5
// 4664.146 us; speedup vs baseline: 1.4891x; 1.4891x over previous
//
#include <hip/hip_runtime.h>
#include <math.h>

// Sizes fixed by the problem.
#define B_TOT 131072
#define M_N   1024
#define BS    128      // Cholesky block size
#define NBK   8        // M_N / BS

typedef float  f32x4  __attribute__((ext_vector_type(4)));
typedef short  bf16x8 __attribute__((ext_vector_type(8)));

// Workspace layout (bytes). Total ~20.3 MB.
enum : size_t {
    OFF_K   = 0,                          // fp64 K / L              8 MB
    OFF_WF  = (size_t)8 << 20,            // fp32 W (full lower)     4 MB
    OFF_W11 = (size_t)12 << 20,           // fp64 W11 diag blocks    1 MB
    OFF_PD  = (size_t)16 << 20,           // fp64 params (6)
    OFF_PF  = ((size_t)16 << 20) + 256,   // fp32 params (6)
    OFF_ZD  = ((size_t)16 << 20) + 512,   // fp64 Zs [1024][5]
    OFF_ZT  = OFF_ZD + (size_t)M_N * 5 * 8,    // fp32 Zs_t [5][1024]
    OFF_WPH = OFF_ZT + (size_t)M_N * 5 * 4,    // bf16 W packed hi    2 MB
    OFF_WPL = OFF_WPH + (size_t)M_N * M_N * 2, // bf16 W packed lo    2 MB
};

__device__ __constant__ double c_zscale[5] = {0.15, 0.1, 0.05, 800.0, 20.0};
__device__ __constant__ double c_zshift[5] = {0.0, 0.0, 0.0, 600.0, 5.0};

static __device__ __forceinline__ unsigned short f2bf(float f) {
    unsigned u = __float_as_uint(f);
    unsigned r = (u + 0x7fff + ((u >> 16) & 1)) >> 16;   // RNE
    return (unsigned short)r;
}
static __device__ __forceinline__ float bf2f(unsigned short s) {
    return __uint_as_float(((unsigned)s) << 16);
}

// ---------------- params ----------------
__global__ void kw_prep(const float* __restrict__ log_ls, const float* __restrict__ log_var,
                        double* __restrict__ pd, float* __restrict__ pf) {
    int t = threadIdx.x;
    if (t < 5) {
        double ls  = exp((double)log_ls[t]);
        double inv = 1.0 / (ls + 1e-8);
        pd[t] = inv; pf[t] = (float)inv;
    }
    if (t == 5) {
        double pv = exp((double)log_var[0]);
        pd[5] = pv; pf[5] = (float)pv;
    }
}

// ---------------- scaled inducing points ----------------
__global__ void kw_prepz(const float* __restrict__ Zraw, const double* __restrict__ pd,
                         double* __restrict__ Zsd, float* __restrict__ Zst) {
    int m = blockIdx.x * 256 + threadIdx.x;
    if (m >= M_N) return;
#pragma unroll
    for (int d = 0; d < 5; ++d) {
        double z  = (double)Zraw[m * 5 + d] * c_zscale[d] + c_zshift[d];
        double zs = z * pd[d];
        Zsd[m * 5 + d]   = zs;
        Zst[d * M_N + m] = (float)zs;
    }
}

// ---------------- K = matern52 + jitter (fp64) ----------------
__global__ void kw_buildK(const double* __restrict__ Zsd, const double* __restrict__ pd,
                          double* __restrict__ Kd) {
    int idx = blockIdx.x * 256 + threadIdx.x;
    int i = idx >> 10, j = idx & 1023;
    double d2 = 0.0;
#pragma unroll
    for (int d = 0; d < 5; ++d) {
        double df = Zsd[i * 5 + d] - Zsd[j * 5 + d];
        d2 += df * df;
    }
    double dd = d2 + 1e-8;
    double dist = sqrt(dd);
    double s = 2.2360679774997896 * dist;
    double v = pd[5] * (1.0 + s + (5.0 / 3.0) * dd) * exp(-s);
    if (i == j) v += 1e-4;
    Kd[(size_t)idx] = v;
}

// ---------------- Cholesky diag block + W11 = inv(L11); uniform predicated loops ------
// W11 -> fp64 Wd11[kb] (for panel TRSM) and fp32 Wf diag block (for trtri/pack).
__global__ __launch_bounds__(256) void kw_diag(double* __restrict__ Kd,
                                               double* __restrict__ Wd11,
                                               float* __restrict__ Wf, int kb) {
    __shared__ double As[128][129];   // lower: A/L ; upper [c][r] (r>c): X = inv(L)
    __shared__ double sinv[128];
    int tid = threadIdx.x;
    int r0 = kb * BS;
    for (int idx = tid; idx < BS * BS; idx += 256) {
        int rr = idx >> 7, cc = idx & 127;
        As[rr][cc] = Kd[(size_t)(r0 + rr) * M_N + r0 + cc];
    }
    __syncthreads();

    int r = tid & 127;
    int half = tid >> 7;
    for (int p = 0; p < 16; ++p) {
        int j0 = p * 8;
        for (int j = j0; j < j0 + 8; ++j) {
            if (tid == j) {
                double d = sqrt(As[j][j]);
                As[j][j] = d;
                sinv[j] = 1.0 / d;
            }
            __syncthreads();
            double arj = 0.0;
            if (half == 0 && r > j) {
                arj = As[r][j] * sinv[j];
                As[r][j] = arj;
            }
            __syncthreads();
            if (half == 0 && r > j) {
#pragma unroll
                for (int c = j + 1; c < j0 + 8; ++c)     // uniform trip
                    As[r][c] -= arj * As[c][j];          // As[c][j]: broadcast
            }
            // next col's reads touch only this thread's own writes -> no barrier
        }
        __syncthreads();
        // rank-8 trailing update: uniform c loop, predicate r >= c
        if (p < 15) {
            double a[8];
#pragma unroll
            for (int t = 0; t < 8; ++t) a[t] = As[r][j0 + t];
            for (int c = j0 + 8 + half; c < 128; c += 2) {
                if (r >= c) {
                    double s = As[r][c];
#pragma unroll
                    for (int t = 0; t < 8; ++t) s -= a[t] * As[c][j0 + t];  // broadcast
                    As[r][c] = s;
                }
            }
        }
        __syncthreads();
    }

    // W11 = inv(L11): thread c (<128) owns column c; X[t][c] stored at As[c][t] (t>c)
    if (tid < 128) {
        int c = tid;
        for (int rb = 0; rb < 16; ++rb) {
            int r0b = rb * 8;
            if (c >= r0b + 8) continue;
            double s[8];
#pragma unroll
            for (int i = 0; i < 8; ++i) s[i] = 0.0;
            for (int t = 0; t < r0b; ++t) {
                if (t >= c) {
                    double xt = (t == c) ? sinv[c] : As[c][t];
#pragma unroll
                    for (int i = 0; i < 8; ++i) s[i] += As[r0b + i][t] * xt;  // broadcast L
                }
            }
            double xloc[8];
#pragma unroll
            for (int i = 0; i < 8; ++i) {
                int rr = r0b + i;
                double v = 0.0;
                if (rr >= c) {
                    v = ((rr == c) ? 1.0 : 0.0) - s[i];
#pragma unroll
                    for (int t2 = 0; t2 < i; ++t2) {
                        int tt = r0b + t2;
                        if (tt >= c) v -= As[rr][tt] * xloc[t2];
                    }
                    v *= sinv[rr];
                    if (rr > c) As[c][rr] = v;
                }
                xloc[i] = v;
            }
        }
    }
    __syncthreads();
    for (int idx = tid; idx < BS * BS; idx += 256) {
        int rr = idx >> 7, cc = idx & 127;
        if (rr >= cc) {
            double v = (rr == cc) ? sinv[rr] : As[cc][rr];
            Wd11[(size_t)kb * BS * BS + rr * BS + cc] = v;
            Wf[(size_t)(r0 + rr) * M_N + r0 + cc] = (float)v;
        }
    }
}

// ---------------- panel: L21 strip = A21 * W11^T (fp64) ----------------
__global__ __launch_bounds__(256) void kw_panel(double* __restrict__ Kd,
                                                const double* __restrict__ Wd11, int kb) {
    __shared__ double As[64][16];
    __shared__ double Ws[16][128];
    int tid = threadIdx.x;
    int row0 = (kb + 1) * BS + blockIdx.x * 64;
    int cb = kb * BS;
    int c = tid & 127, q = tid >> 7;
    double acc[32];
#pragma unroll
    for (int i = 0; i < 32; ++i) acc[i] = 0.0;
    for (int tc = 0; tc < 8; ++tc) {
        int tb = tc * 16;
        for (int idx = tid; idx < 64 * 16; idx += 256) {
            int rr = idx >> 4, tt = idx & 15;
            As[rr][tt] = Kd[(size_t)(row0 + rr) * M_N + cb + tb + tt];
        }
        for (int idx = tid; idx < 128 * 16; idx += 256) {
            int cc = idx >> 4, tt = idx & 15;
            Ws[tt][cc] = (tb + tt <= cc) ? Wd11[(size_t)kb * BS * BS + cc * BS + tb + tt] : 0.0;
        }
        __syncthreads();
#pragma unroll
        for (int t = 0; t < 16; ++t) {
            double w = Ws[t][c];
#pragma unroll
            for (int i = 0; i < 32; ++i) acc[i] += As[q * 32 + i][t] * w;
        }
        __syncthreads();
    }
#pragma unroll
    for (int i = 0; i < 32; ++i)
        Kd[(size_t)(row0 + q * 32 + i) * M_N + cb + c] = acc[i];
}

// ---------------- trailing update: A22 -= L21 * L21^T (fp64, lower tiles) -------------
__global__ __launch_bounds__(256) void kw_update(double* __restrict__ Kd, int kb) {
    __shared__ double As2[64][17];
    __shared__ double Bs2[64][17];
    int tid = threadIdx.x;
    int v = blockIdx.x;
    int by = 0;
    while ((by + 1) * (by + 2) / 2 <= v) ++by;
    int bx = v - by * (by + 1) / 2;
    int base = (kb + 1) * BS;
    int gr0 = base + by * 64;
    int gc0 = base + bx * 64;
    int cb = kb * BS;
    int tx = tid & 15, ty = tid >> 4;
    double acc[4][4];
#pragma unroll
    for (int i = 0; i < 4; ++i)
#pragma unroll
        for (int j = 0; j < 4; ++j) acc[i][j] = 0.0;
    for (int tc = 0; tc < 8; ++tc) {
        int tb = tc * 16;
        for (int idx = tid; idx < 1024; idx += 256) {
            int rr = idx >> 4, tt = idx & 15;
            As2[rr][tt] = Kd[(size_t)(gr0 + rr) * M_N + cb + tb + tt];
            Bs2[rr][tt] = Kd[(size_t)(gc0 + rr) * M_N + cb + tb + tt];
        }
        __syncthreads();
#pragma unroll
        for (int t = 0; t < 16; ++t) {
            double a[4], b[4];
#pragma unroll
            for (int i = 0; i < 4; ++i) a[i] = As2[ty * 4 + i][t];
#pragma unroll
            for (int j = 0; j < 4; ++j) b[j] = Bs2[tx * 4 + j][t];
#pragma unroll
            for (int i = 0; i < 4; ++i)
#pragma unroll
                for (int j = 0; j < 4; ++j) acc[i][j] += a[i] * b[j];
        }
        __syncthreads();
    }
#pragma unroll
    for (int i = 0; i < 4; ++i)
#pragma unroll
        for (int j = 0; j < 4; ++j)
            Kd[(size_t)(gr0 + ty * 4 + i) * M_N + gc0 + tx * 4 + j] -= acc[i][j];
}

// ---------------- trtri: single launch, fp32, per (col-block j, 32-col tile) ----------
// Each block sequentially computes W_ij (i = j+1..7) for its 32 cols, keeping its own
// prior W tiles in an LDS history ring (no global RAW within the block).
__global__ __launch_bounds__(512) void kw_trtri(const double* __restrict__ Kd,
                                                float* __restrict__ Wf) {
    __shared__ float Ls[128][33];            // L / W_ii K-chunk
    __shared__ float Ws[32][33];             // W_jj K-chunk (t == j)
    __shared__ float Whist[6][128][33];      // this block's W_t tiles, t-j-1
    __shared__ float Ps[128][33];            // P tile
    int j  = blockIdx.y;                     // 0..6
    int ct = blockIdx.x;                     // 0..3
    int c0 = j * BS + ct * 32;
    int tid = threadIdx.x;
    int rq = tid >> 2, cq = tid & 3;         // row rq, cols cq*8..cq*8+7

    for (int i = j + 1; i < 8; ++i) {
        float acc[8];
#pragma unroll
        for (int c = 0; c < 8; ++c) acc[c] = 0.0f;
        // P = sum_{t=j}^{i-1} L_it * W_t(cols)
        for (int t = j; t < i; ++t) {
            for (int ch = 0; ch < 4; ++ch) {
                int tb = t * BS + ch * 32;
                __syncthreads();             // Ls reuse safe
                for (int idx = tid; idx < 128 * 32; idx += 512) {
                    int rr = idx >> 5, tt = idx & 31;
                    Ls[rr][tt] = (float)Kd[(size_t)(i * BS + rr) * M_N + tb + tt];
                }
                if (t == j) {
                    for (int idx = tid; idx < 32 * 32; idx += 512) {
                        int tt = idx >> 5, cc = idx & 31;
                        int gr = tb + tt, gc = c0 + cc;
                        Ws[tt][cc] = (gr >= gc) ? Wf[(size_t)gr * M_N + gc] : 0.0f;
                    }
                }
                __syncthreads();
                if (t == j) {
#pragma unroll
                    for (int tt = 0; tt < 32; ++tt) {
                        float l = Ls[rq][tt];
#pragma unroll
                        for (int c = 0; c < 8; ++c)
                            acc[c] = fmaf(l, Ws[tt][cq * 8 + c], acc[c]);
                    }
                } else {
                    const float (*Wh)[33] = Whist[t - j - 1];
#pragma unroll
                    for (int tt = 0; tt < 32; ++tt) {
                        float l = Ls[rq][tt];
#pragma unroll
                        for (int c = 0; c < 8; ++c)
                            acc[c] = fmaf(l, Wh[ch * 32 + tt][cq * 8 + c], acc[c]);
                    }
                }
            }
        }
        __syncthreads();
#pragma unroll
        for (int c = 0; c < 8; ++c) Ps[rq][cq * 8 + c] = acc[c];
        // W_ij = -W_ii * P
        float a2[8];
#pragma unroll
        for (int c = 0; c < 8; ++c) a2[c] = 0.0f;
        for (int ch = 0; ch < 4; ++ch) {
            __syncthreads();
            for (int idx = tid; idx < 128 * 32; idx += 512) {
                int rr = idx >> 5, tt = idx & 31;
                Ls[rr][tt] = (rr >= ch * 32 + tt)
                           ? Wf[(size_t)(i * BS + rr) * M_N + i * BS + ch * 32 + tt] : 0.0f;
            }
            __syncthreads();
#pragma unroll
            for (int tt = 0; tt < 32; ++tt) {
                float l = Ls[rq][tt];
#pragma unroll
                for (int c = 0; c < 8; ++c)
                    a2[c] = fmaf(l, Ps[ch * 32 + tt][cq * 8 + c], a2[c]);
            }
        }
        __syncthreads();
#pragma unroll
        for (int c = 0; c < 8; ++c) {
            float v = -a2[c];
            Wf[(size_t)(i * BS + rq) * M_N + c0 + cq * 8 + c] = v;
            if (i < 7) Whist[i - j - 1][rq][cq * 8 + c] = v;
        }
        __syncthreads();
    }
}

// ---------------- pack W (fp32) into MFMA B-fragment order, bf16 hi/lo ----------------
__global__ void kw_pack(const float* __restrict__ Wf, short* __restrict__ Wph,
                        short* __restrict__ Wpl) {
    int T = blockIdx.x * 256 + threadIdx.x;
    int lane = T & 63, fid = T >> 6;
    int jn = fid & 63, kik = fid >> 6;
    int ki = kik & 3, kc = kik >> 2;
    int j  = jn * 16 + (lane & 15);
    int kb = kc * 128 + ki * 32 + (lane >> 4) * 8;
    bf16x8 h, lo;
#pragma unroll
    for (int e = 0; e < 8; ++e) {
        int k = kb + e;
        float v = (k <= j) ? Wf[(size_t)j * M_N + k] : 0.0f;
        unsigned short hb = f2bf(v);
        h[e]  = (short)hb;
        lo[e] = (short)f2bf(v - bf2f(hb));
    }
    size_t off = (size_t)fid * 512 + lane * 8;
    *(bf16x8*)(Wph + off) = h;
    *(bf16x8*)(Wpl + off) = lo;
}

// ---------------- main MFMA kernel: 32 rows x 1024 cols, single k-buffer --------------
__global__ __launch_bounds__(512, 4) void k_mm(const float* __restrict__ x_star,
                                               const float* __restrict__ pf,
                                               const float* __restrict__ Zs_t,
                                               const short* __restrict__ Wph,
                                               const short* __restrict__ Wpl,
                                               float* __restrict__ out, int Bq) {
    __shared__ __align__(16) char kls[2][32 * 256];  // [hi/lo][row][256B], swizzled
    __shared__ float red_l[32];
    int tid  = threadIdx.x;
    int slab = blockIdx.x;
    int w = tid >> 6, lane = tid & 63;
    int lrow = lane & 15, kgrp = lane >> 4;

    // staging identity: this thread always stages row srow, col-group scc
    int srow = tid >> 4, scc = tid & 15;
    int qrow = slab * 32 + srow;
    int qc = (qrow < Bq) ? qrow : (Bq - 1);
    float xv0 = x_star[(size_t)qc * 5 + 0] * pf[0];
    float xv1 = x_star[(size_t)qc * 5 + 1] * pf[1];
    float xv2 = x_star[(size_t)qc * 5 + 2] * pf[2];
    float xv3 = x_star[(size_t)qc * 5 + 3] * pf[3];
    float xv4 = x_star[(size_t)qc * 5 + 4] * pf[4];
    float pv = pf[5];
    if (tid < 32) red_l[tid] = 0.0f;

    f32x4 acc[2][8];
#pragma unroll
    for (int mi = 0; mi < 2; ++mi)
#pragma unroll
        for (int nj = 0; nj < 8; ++nj) acc[mi][nj] = (f32x4)(0.0f);

    int jmax_w = (56 + w) * 16 + 15;   // wave's max output column (jng = w + 8*nj)
    int soff = srow * 256 + ((scc * 16) ^ ((srow & 15) << 4));

    for (int kc = 0; kc < 8; ++kc) {
        // ---- stage k chunk (32 rows x 128 cols), bf16 hi/lo ----
        int lb = kc * 128 + scc * 8;
        float z0[8], z1[8], z2[8], z3[8], z4[8];
        *(float4*)&z0[0] = *(const float4*)&Zs_t[lb];
        *(float4*)&z0[4] = *(const float4*)&Zs_t[lb + 4];
        *(float4*)&z1[0] = *(const float4*)&Zs_t[M_N + lb];
        *(float4*)&z1[4] = *(const float4*)&Zs_t[M_N + lb + 4];
        *(float4*)&z2[0] = *(const float4*)&Zs_t[2 * M_N + lb];
        *(float4*)&z2[4] = *(const float4*)&Zs_t[2 * M_N + lb + 4];
        *(float4*)&z3[0] = *(const float4*)&Zs_t[3 * M_N + lb];
        *(float4*)&z3[4] = *(const float4*)&Zs_t[3 * M_N + lb + 4];
        *(float4*)&z4[0] = *(const float4*)&Zs_t[4 * M_N + lb];
        *(float4*)&z4[4] = *(const float4*)&Zs_t[4 * M_N + lb + 4];
        bf16x8 hv, lv;
#pragma unroll
        for (int e = 0; e < 8; ++e) {
            float dx0 = xv0 - z0[e], dx1 = xv1 - z1[e], dx2 = xv2 - z2[e],
                  dx3 = xv3 - z3[e], dx4 = xv4 - z4[e];
            float d2 = dx0 * dx0 + dx1 * dx1 + dx2 * dx2 + dx3 * dx3 + dx4 * dx4;
            float ddv = d2 + 1e-8f;
            float dist = sqrtf(ddv);
            float sv = 2.23606798f * dist;
            float kvf = pv * (1.0f + sv + 1.66666667f * ddv) * __expf(-sv);
            unsigned short hb = f2bf(kvf);
            hv[e] = (short)hb;
            lv[e] = (short)f2bf(kvf - bf2f(hb));
        }
        __syncthreads();                  // prior-chunk MFMA reads done
        *(bf16x8*)(&kls[0][soff]) = hv;
        *(bf16x8*)(&kls[1][soff]) = lv;
        __syncthreads();                  // chunk visible

        // ---- MFMA over this K chunk ----
        for (int ki = 0; ki < 4; ++ki) {
            int kmin = kc * 128 + ki * 32;
            if (kmin > jmax_w) break;            // wave-uniform
            bf16x8 Ah[2], Al[2];
#pragma unroll
            for (int mi = 0; mi < 2; ++mi) {
                int row = mi * 16 + lrow;
                int cb  = ki * 64 + kgrp * 16;
                int off = row * 256 + (cb ^ ((row & 15) << 4));
                Ah[mi] = *(const bf16x8*)(&kls[0][off]);
                Al[mi] = *(const bf16x8*)(&kls[1][off]);
            }
#pragma unroll
            for (int nj = 0; nj < 8; ++nj) {
                int jng = w + 8 * nj;                 // balanced col interleave
                if (kmin > jng * 16 + 15) continue;   // all-zero W fragment
                size_t fo = ((size_t)((kc * 4 + ki) * 64 + jng)) * 512 + lane * 8;
                bf16x8 Bh = *(const bf16x8*)(Wph + fo);
                bf16x8 Bl = *(const bf16x8*)(Wpl + fo);
#pragma unroll
                for (int mi = 0; mi < 2; ++mi) {
                    acc[mi][nj] = __builtin_amdgcn_mfma_f32_16x16x32_bf16(Ah[mi], Bh, acc[mi][nj], 0, 0, 0);
                    acc[mi][nj] = __builtin_amdgcn_mfma_f32_16x16x32_bf16(Ah[mi], Bl, acc[mi][nj], 0, 0, 0);
                    acc[mi][nj] = __builtin_amdgcn_mfma_f32_16x16x32_bf16(Al[mi], Bh, acc[mi][nj], 0, 0, 0);
                }
            }
        }
    }

    // epilogue: red[row] += y^2 ; C layout: row = mi*16 + kgrp*4 + q, col = jng*16 + lrow
#pragma unroll
    for (int mi = 0; mi < 2; ++mi) {
#pragma unroll
        for (int q = 0; q < 4; ++q) {
            float s = 0.0f;
#pragma unroll
            for (int nj = 0; nj < 8; ++nj) s = fmaf(acc[mi][nj][q], acc[mi][nj][q], s);
            s += __shfl_xor(s, 1);
            s += __shfl_xor(s, 2);
            s += __shfl_xor(s, 4);
            s += __shfl_xor(s, 8);
            if (lrow == 0) atomicAdd(&red_l[mi * 16 + kgrp * 4 + q], s);
        }
    }
    __syncthreads();
    if (tid < 32) {
        int b = slab * 32 + tid;
        if (b < Bq) out[b] = sqrtf(fmaxf(pv - red_l[tid], 1e-6f));
    }
}

extern "C" void kernel_launch(void* const* d_in, const int* in_sizes, int n_in,
                              void* d_out, int out_size, void* d_ws, size_t ws_size,
                              hipStream_t stream) {
    const float* x_star  = (const float*)d_in[0];
    const float* log_ls  = (const float*)d_in[1];
    const float* log_var = (const float*)d_in[2];
    const float* Z_raw   = (const float*)d_in[3];
    float* out = (float*)d_out;
    int Bq = in_sizes[0] / 5;

    char* ws = (char*)d_ws;
    double* Kd   = (double*)(ws + OFF_K);
    float*  Wf   = (float*)(ws + OFF_WF);
    double* Wd11 = (double*)(ws + OFF_W11);
    double* pd   = (double*)(ws + OFF_PD);
    float*  pf   = (float*)(ws + OFF_PF);
    double* Zsd  = (double*)(ws + OFF_ZD);
    float*  Zst  = (float*)(ws + OFF_ZT);
    short*  Wph  = (short*)(ws + OFF_WPH);
    short*  Wpl  = (short*)(ws + OFF_WPL);

    kw_prep<<<1, 64, 0, stream>>>(log_ls, log_var, pd, pf);
    kw_prepz<<<4, 256, 0, stream>>>(Z_raw, pd, Zsd, Zst);
    kw_buildK<<<4096, 256, 0, stream>>>(Zsd, pd, Kd);

    for (int kb = 0; kb < NBK; ++kb) {
        kw_diag<<<1, 256, 0, stream>>>(Kd, Wd11, Wf, kb);
        int R = M_N - (kb + 1) * BS;
        if (R > 0) {
            int nt = R / 64;
            kw_panel<<<nt, 256, 0, stream>>>(Kd, Wd11, kb);
            kw_update<<<nt * (nt + 1) / 2, 256, 0, stream>>>(Kd, kb);
        }
    }
    kw_trtri<<<dim3(4, 7), 512, 0, stream>>>(Kd, Wf);
    kw_pack<<<512, 256, 0, stream>>>(Wf, Wph, Wpl);

    int slabs = (Bq + 31) / 32;
    k_mm<<<slabs, 512, 0, stream>>>(x_star, pf, Zst, Wph, Wpl, out, Bq);
}

// Round 6
// 3727.210 us; speedup vs baseline: 1.8635x; 1.2514x over previous
//
#include <hip/hip_runtime.h>
#include <math.h>

// Sizes fixed by the problem.
#define B_TOT 131072
#define M_N   1024
#define BS    128      // Cholesky block size
#define NBK   8        // M_N / BS

typedef float  f32x4  __attribute__((ext_vector_type(4)));
typedef short  bf16x8 __attribute__((ext_vector_type(8)));

// Workspace layout (bytes). Total ~18 MB.
enum : size_t {
    OFF_K   = 0,                          // fp64 K / L              8 MB
    OFF_WF  = (size_t)8 << 20,            // fp32 W (full lower)     4 MB
    OFF_W11 = (size_t)12 << 20,           // fp64 W11 diag blocks    1 MB
    OFF_PF  = (size_t)13 << 20,           // fp32 params (6)
    OFF_ZT  = ((size_t)13 << 20) + 256,   // fp32 Zs_t [5][1024]     20 KB
    OFF_WPH = (size_t)14 << 20,           // bf16 W packed hi        2 MB
    OFF_WPL = (size_t)16 << 20,           // bf16 W packed lo        2 MB
};

__device__ __constant__ double c_zscale[5] = {0.15, 0.1, 0.05, 800.0, 20.0};
__device__ __constant__ double c_zshift[5] = {0.0, 0.0, 0.0, 600.0, 5.0};

static __device__ __forceinline__ unsigned short f2bf(float f) {
    unsigned u = __float_as_uint(f);
    unsigned r = (u + 0x7fff + ((u >> 16) & 1)) >> 16;   // RNE
    return (unsigned short)r;
}
static __device__ __forceinline__ float bf2f(unsigned short s) {
    return __uint_as_float(((unsigned)s) << 16);
}

// ---------------- fused: params + Zs + K = matern52 + jitter (fp64) ----------------
// grid 4096 x 256; block b covers K row i = b>>2, cols (b&3)*256 + tid.
__global__ __launch_bounds__(256) void k_build(const float* __restrict__ log_ls,
                                               const float* __restrict__ log_var,
                                               const float* __restrict__ Zraw,
                                               double* __restrict__ Kd,
                                               float* __restrict__ pf,
                                               float* __restrict__ Zst) {
    __shared__ double pd[6];
    __shared__ double zsi[5];
    int tid = threadIdx.x;
    if (tid < 5) pd[tid] = 1.0 / (exp((double)log_ls[tid]) + 1e-8);
    if (tid == 5) pd[5] = exp((double)log_var[0]);
    __syncthreads();
    int i = blockIdx.x >> 2;
    int j = (blockIdx.x & 3) * 256 + tid;
    if (tid < 5) zsi[tid] = ((double)Zraw[i * 5 + tid] * c_zscale[tid] + c_zshift[tid]) * pd[tid];
    __syncthreads();
    double d2 = 0.0;
#pragma unroll
    for (int d = 0; d < 5; ++d) {
        double zj = ((double)Zraw[j * 5 + d] * c_zscale[d] + c_zshift[d]) * pd[d];
        double df = zsi[d] - zj;
        d2 += df * df;
    }
    double dd = d2 + 1e-8;
    double dist = sqrt(dd);
    double s = 2.2360679774997896 * dist;
    double v = pd[5] * (1.0 + s + (5.0 / 3.0) * dd) * exp(-s);
    if (i == j) v += 1e-4;
    Kd[(size_t)i * M_N + j] = v;
    // side outputs for k_mm
    if (blockIdx.x < 4) {
        int m = blockIdx.x * 256 + tid;
#pragma unroll
        for (int d = 0; d < 5; ++d)
            Zst[d * M_N + m] = (float)(((double)Zraw[m * 5 + d] * c_zscale[d] + c_zshift[d]) * pd[d]);
    }
    if (blockIdx.x == 4 && tid < 6) pf[tid] = (float)pd[tid];
}

// ---------------- Cholesky diag block (512 thr) + W11 = inv(L11) ----------------
__global__ __launch_bounds__(512) void kw_diag(double* __restrict__ Kd,
                                               double* __restrict__ Wd11,
                                               float* __restrict__ Wf, int kb) {
    __shared__ double As[128][129];   // lower: A/L ; upper [c][r] (r>c): X = inv(L)
    __shared__ double sinv[128];
    int tid = threadIdx.x;
    int r0 = kb * BS;
    for (int idx = tid; idx < BS * BS; idx += 512) {
        int rr = idx >> 7, cc = idx & 127;
        As[rr][cc] = Kd[(size_t)(r0 + rr) * M_N + r0 + cc];
    }
    __syncthreads();

    int r = tid & 127;
    int q = tid >> 7;                 // quarter 0..3
    for (int p = 0; p < 16; ++p) {
        int j0 = p * 8;
        for (int j = j0; j < j0 + 8; ++j) {
            if (tid == j) {
                double d = sqrt(As[j][j]);
                As[j][j] = d;
                sinv[j] = 1.0 / d;
            }
            __syncthreads();
            double arj = 0.0;
            if (q == 0 && r > j) {
                arj = As[r][j] * sinv[j];
                As[r][j] = arj;
            }
            __syncthreads();
            if (q == 0 && r > j) {
#pragma unroll
                for (int c = j + 1; c < j0 + 8; ++c)     // uniform trip, own-row writes
                    As[r][c] -= arj * As[c][j];          // As[c][j]: broadcast
            }
        }
        __syncthreads();
        // rank-8 trailing update, 4-way split over quarters
        if (p < 15) {
            double a[8];
#pragma unroll
            for (int t = 0; t < 8; ++t) a[t] = As[r][j0 + t];
            for (int c = j0 + 8 + q; c < 128; c += 4) {
                if (r >= c) {
                    double s = As[r][c];
#pragma unroll
                    for (int t = 0; t < 8; ++t) s -= a[t] * As[c][j0 + t];  // broadcast
                    As[r][c] = s;
                }
            }
        }
        __syncthreads();
    }

    // W11 = inv(L11): thread c (<128) owns column c; X[t][c] stored at As[c][t] (t>c)
    if (tid < 128) {
        int c = tid;
        for (int rb = 0; rb < 16; ++rb) {
            int r0b = rb * 8;
            if (c >= r0b + 8) continue;
            double s[8];
#pragma unroll
            for (int i = 0; i < 8; ++i) s[i] = 0.0;
            for (int t = 0; t < r0b; ++t) {
                if (t >= c) {
                    double xt = (t == c) ? sinv[c] : As[c][t];
#pragma unroll
                    for (int i = 0; i < 8; ++i) s[i] += As[r0b + i][t] * xt;  // broadcast L
                }
            }
            double xloc[8];
#pragma unroll
            for (int i = 0; i < 8; ++i) {
                int rr = r0b + i;
                double v = 0.0;
                if (rr >= c) {
                    v = ((rr == c) ? 1.0 : 0.0) - s[i];
#pragma unroll
                    for (int t2 = 0; t2 < i; ++t2) {
                        int tt = r0b + t2;
                        if (tt >= c) v -= As[rr][tt] * xloc[t2];
                    }
                    v *= sinv[rr];
                    if (rr > c) As[c][rr] = v;
                }
                xloc[i] = v;
            }
        }
    }
    __syncthreads();
    for (int idx = tid; idx < BS * BS; idx += 512) {
        int rr = idx >> 7, cc = idx & 127;
        if (rr >= cc) {
            double v = (rr == cc) ? sinv[rr] : As[cc][rr];
            Wd11[(size_t)kb * BS * BS + rr * BS + cc] = v;
            Wf[(size_t)(r0 + rr) * M_N + r0 + cc] = (float)v;
        }
    }
}

// ---------------- panel: L21 strip = A21 * W11^T (fp64) ----------------
__global__ __launch_bounds__(256) void kw_panel(double* __restrict__ Kd,
                                                const double* __restrict__ Wd11, int kb) {
    __shared__ double As[64][16];
    __shared__ double Ws[16][128];
    int tid = threadIdx.x;
    int row0 = (kb + 1) * BS + blockIdx.x * 64;
    int cb = kb * BS;
    int c = tid & 127, q = tid >> 7;
    double acc[32];
#pragma unroll
    for (int i = 0; i < 32; ++i) acc[i] = 0.0;
    for (int tc = 0; tc < 8; ++tc) {
        int tb = tc * 16;
        for (int idx = tid; idx < 64 * 16; idx += 256) {
            int rr = idx >> 4, tt = idx & 15;
            As[rr][tt] = Kd[(size_t)(row0 + rr) * M_N + cb + tb + tt];
        }
        for (int idx = tid; idx < 128 * 16; idx += 256) {
            int cc = idx >> 4, tt = idx & 15;
            Ws[tt][cc] = (tb + tt <= cc) ? Wd11[(size_t)kb * BS * BS + cc * BS + tb + tt] : 0.0;
        }
        __syncthreads();
#pragma unroll
        for (int t = 0; t < 16; ++t) {
            double w = Ws[t][c];
#pragma unroll
            for (int i = 0; i < 32; ++i) acc[i] += As[q * 32 + i][t] * w;
        }
        __syncthreads();
    }
#pragma unroll
    for (int i = 0; i < 32; ++i)
        Kd[(size_t)(row0 + q * 32 + i) * M_N + cb + c] = acc[i];
}

// ---------------- trailing update: A22 -= L21 * L21^T (fp64, lower tiles) -------------
__global__ __launch_bounds__(256) void kw_update(double* __restrict__ Kd, int kb) {
    __shared__ double As2[64][17];
    __shared__ double Bs2[64][17];
    int tid = threadIdx.x;
    int v = blockIdx.x;
    int by = 0;
    while ((by + 1) * (by + 2) / 2 <= v) ++by;
    int bx = v - by * (by + 1) / 2;
    int base = (kb + 1) * BS;
    int gr0 = base + by * 64;
    int gc0 = base + bx * 64;
    int cb = kb * BS;
    int tx = tid & 15, ty = tid >> 4;
    double acc[4][4];
#pragma unroll
    for (int i = 0; i < 4; ++i)
#pragma unroll
        for (int j = 0; j < 4; ++j) acc[i][j] = 0.0;
    for (int tc = 0; tc < 8; ++tc) {
        int tb = tc * 16;
        for (int idx = tid; idx < 1024; idx += 256) {
            int rr = idx >> 4, tt = idx & 15;
            As2[rr][tt] = Kd[(size_t)(gr0 + rr) * M_N + cb + tb + tt];
            Bs2[rr][tt] = Kd[(size_t)(gc0 + rr) * M_N + cb + tb + tt];
        }
        __syncthreads();
#pragma unroll
        for (int t = 0; t < 16; ++t) {
            double a[4], b[4];
#pragma unroll
            for (int i = 0; i < 4; ++i) a[i] = As2[ty * 4 + i][t];
#pragma unroll
            for (int j = 0; j < 4; ++j) b[j] = Bs2[tx * 4 + j][t];
#pragma unroll
            for (int i = 0; i < 4; ++i)
#pragma unroll
                for (int j = 0; j < 4; ++j) acc[i][j] += a[i] * b[j];
        }
        __syncthreads();
    }
#pragma unroll
    for (int i = 0; i < 4; ++i)
#pragma unroll
        for (int j = 0; j < 4; ++j)
            Kd[(size_t)(gr0 + ty * 4 + i) * M_N + gc0 + tx * 4 + j] -= acc[i][j];
}

// ---------------- trtri: single launch, fp32, per (col-block j, 32-col tile) ----------
__global__ __launch_bounds__(512) void kw_trtri(const double* __restrict__ Kd,
                                                float* __restrict__ Wf) {
    __shared__ float Ls[128][33];            // L / W_ii K-chunk
    __shared__ float Ws[32][33];             // W_jj K-chunk (t == j)
    __shared__ float Whist[6][128][33];      // this block's W_t tiles, t-j-1
    __shared__ float Ps[128][33];            // P tile
    int j  = blockIdx.y;                     // 0..6
    int ct = blockIdx.x;                     // 0..3
    int c0 = j * BS + ct * 32;
    int tid = threadIdx.x;
    int rq = tid >> 2, cq = tid & 3;         // row rq, cols cq*8..cq*8+7

    for (int i = j + 1; i < 8; ++i) {
        float acc[8];
#pragma unroll
        for (int c = 0; c < 8; ++c) acc[c] = 0.0f;
        for (int t = j; t < i; ++t) {
            for (int ch = 0; ch < 4; ++ch) {
                int tb = t * BS + ch * 32;
                __syncthreads();             // Ls reuse safe
                for (int idx = tid; idx < 128 * 32; idx += 512) {
                    int rr = idx >> 5, tt = idx & 31;
                    Ls[rr][tt] = (float)Kd[(size_t)(i * BS + rr) * M_N + tb + tt];
                }
                if (t == j) {
                    for (int idx = tid; idx < 32 * 32; idx += 512) {
                        int tt = idx >> 5, cc = idx & 31;
                        int gr = tb + tt, gc = c0 + cc;
                        Ws[tt][cc] = (gr >= gc) ? Wf[(size_t)gr * M_N + gc] : 0.0f;
                    }
                }
                __syncthreads();
                if (t == j) {
#pragma unroll
                    for (int tt = 0; tt < 32; ++tt) {
                        float l = Ls[rq][tt];
#pragma unroll
                        for (int c = 0; c < 8; ++c)
                            acc[c] = fmaf(l, Ws[tt][cq * 8 + c], acc[c]);
                    }
                } else {
                    const float (*Wh)[33] = Whist[t - j - 1];
#pragma unroll
                    for (int tt = 0; tt < 32; ++tt) {
                        float l = Ls[rq][tt];
#pragma unroll
                        for (int c = 0; c < 8; ++c)
                            acc[c] = fmaf(l, Wh[ch * 32 + tt][cq * 8 + c], acc[c]);
                    }
                }
            }
        }
        __syncthreads();
#pragma unroll
        for (int c = 0; c < 8; ++c) Ps[rq][cq * 8 + c] = acc[c];
        float a2[8];
#pragma unroll
        for (int c = 0; c < 8; ++c) a2[c] = 0.0f;
        for (int ch = 0; ch < 4; ++ch) {
            __syncthreads();
            for (int idx = tid; idx < 128 * 32; idx += 512) {
                int rr = idx >> 5, tt = idx & 31;
                Ls[rr][tt] = (rr >= ch * 32 + tt)
                           ? Wf[(size_t)(i * BS + rr) * M_N + i * BS + ch * 32 + tt] : 0.0f;
            }
            __syncthreads();
#pragma unroll
            for (int tt = 0; tt < 32; ++tt) {
                float l = Ls[rq][tt];
#pragma unroll
                for (int c = 0; c < 8; ++c)
                    a2[c] = fmaf(l, Ps[ch * 32 + tt][cq * 8 + c], a2[c]);
            }
        }
        __syncthreads();
#pragma unroll
        for (int c = 0; c < 8; ++c) {
            float v = -a2[c];
            Wf[(size_t)(i * BS + rq) * M_N + c0 + cq * 8 + c] = v;
            if (i < 7) Whist[i - j - 1][rq][cq * 8 + c] = v;
        }
        __syncthreads();
    }
}

// ---------------- pack W (fp32) into MFMA B-fragment order, bf16 hi/lo ----------------
__global__ void kw_pack(const float* __restrict__ Wf, short* __restrict__ Wph,
                        short* __restrict__ Wpl) {
    int T = blockIdx.x * 256 + threadIdx.x;
    int lane = T & 63, fid = T >> 6;
    int jn = fid & 63, kik = fid >> 6;
    int ki = kik & 3, kc = kik >> 2;
    int j  = jn * 16 + (lane & 15);
    int kb = kc * 128 + ki * 32 + (lane >> 4) * 8;
    bf16x8 h, lo;
#pragma unroll
    for (int e = 0; e < 8; ++e) {
        int k = kb + e;
        float v = (k <= j) ? Wf[(size_t)j * M_N + k] : 0.0f;
        unsigned short hb = f2bf(v);
        h[e]  = (short)hb;
        lo[e] = (short)f2bf(v - bf2f(hb));
    }
    size_t off = (size_t)fid * 512 + lane * 8;
    *(bf16x8*)(Wph + off) = h;
    *(bf16x8*)(Wpl + off) = lo;
}

// ---------------- main MFMA kernel: 32 rows x 1024 cols, single k-buffer --------------
__global__ __launch_bounds__(512, 1) void k_mm(const float* __restrict__ x_star,
                                               const float* __restrict__ pf,
                                               const float* __restrict__ Zs_t,
                                               const short* __restrict__ Wph,
                                               const short* __restrict__ Wpl,
                                               float* __restrict__ out, int Bq) {
    __shared__ __align__(16) char kls[2][32 * 256];  // [hi/lo][row][256B], swizzled
    __shared__ float red_l[32];
    int tid  = threadIdx.x;
    int slab = blockIdx.x;
    int w = tid >> 6, lane = tid & 63;
    int lrow = lane & 15, kgrp = lane >> 4;

    // staging identity: this thread stages row srow, col-group scc (8 cols)
    int srow = tid >> 4, scc = tid & 15;
    int qrow = slab * 32 + srow;
    int qc = (qrow < Bq) ? qrow : (Bq - 1);
    float xv0 = x_star[(size_t)qc * 5 + 0] * pf[0];
    float xv1 = x_star[(size_t)qc * 5 + 1] * pf[1];
    float xv2 = x_star[(size_t)qc * 5 + 2] * pf[2];
    float xv3 = x_star[(size_t)qc * 5 + 3] * pf[3];
    float xv4 = x_star[(size_t)qc * 5 + 4] * pf[4];
    float pv = pf[5];
    if (tid < 32) red_l[tid] = 0.0f;

    f32x4 acc[2][8];
#pragma unroll
    for (int mi = 0; mi < 2; ++mi)
#pragma unroll
        for (int nj = 0; nj < 8; ++nj) acc[mi][nj] = (f32x4)(0.0f);

    int jmax_w = (56 + ((w + 7) & 7)) * 16 + 15;   // wave max col, jng = 8nj+((w+nj)&7)
    int soff = srow * 256 + ((scc * 16) ^ ((srow & 15) << 4));

    for (int kc = 0; kc < 8; ++kc) {
        // ---- compute k chunk values (32 rows x 128 cols), bf16 hi/lo ----
        int lb = kc * 128 + scc * 8;
        float kv[8];
#pragma unroll
        for (int h = 0; h < 2; ++h) {
            float z0[4], z1[4], z2[4], z3[4], z4[4];
            *(float4*)z0 = *(const float4*)&Zs_t[lb + 4 * h];
            *(float4*)z1 = *(const float4*)&Zs_t[M_N + lb + 4 * h];
            *(float4*)z2 = *(const float4*)&Zs_t[2 * M_N + lb + 4 * h];
            *(float4*)z3 = *(const float4*)&Zs_t[3 * M_N + lb + 4 * h];
            *(float4*)z4 = *(const float4*)&Zs_t[4 * M_N + lb + 4 * h];
#pragma unroll
            for (int e = 0; e < 4; ++e) {
                float dx0 = xv0 - z0[e], dx1 = xv1 - z1[e], dx2 = xv2 - z2[e],
                      dx3 = xv3 - z3[e], dx4 = xv4 - z4[e];
                float d2 = dx0 * dx0 + dx1 * dx1 + dx2 * dx2 + dx3 * dx3 + dx4 * dx4;
                float ddv = d2 + 1e-8f;
                float dist = sqrtf(ddv);
                float sv = 2.23606798f * dist;
                kv[h * 4 + e] = pv * (1.0f + sv + 1.66666667f * ddv) * __expf(-sv);
            }
        }
        bf16x8 hv, lv;
#pragma unroll
        for (int e = 0; e < 8; ++e) {
            unsigned short hb = f2bf(kv[e]);
            hv[e] = (short)hb;
            lv[e] = (short)f2bf(kv[e] - bf2f(hb));
        }
        __syncthreads();                  // prior-chunk MFMA reads done
        *(bf16x8*)(&kls[0][soff]) = hv;
        *(bf16x8*)(&kls[1][soff]) = lv;
        __syncthreads();                  // chunk visible

        // ---- MFMA over this K chunk ----
        for (int ki = 0; ki < 4; ++ki) {
            int kmin = kc * 128 + ki * 32;
            if (kmin > jmax_w) break;            // wave-uniform
            bf16x8 Ah[2], Al[2];
#pragma unroll
            for (int mi = 0; mi < 2; ++mi) {
                int row = mi * 16 + lrow;
                int cb  = ki * 64 + kgrp * 16;
                int off = row * 256 + (cb ^ ((row & 15) << 4));
                Ah[mi] = *(const bf16x8*)(&kls[0][off]);
                Al[mi] = *(const bf16x8*)(&kls[1][off]);
            }
#pragma unroll
            for (int nj = 0; nj < 8; ++nj) {
                int jng = nj * 8 + ((w + nj) & 7);    // balanced col interleave
                if (kmin > jng * 16 + 15) continue;   // all-zero W fragment
                size_t fo = ((size_t)((kc * 4 + ki) * 64 + jng)) * 512 + lane * 8;
                bf16x8 Bh = *(const bf16x8*)(Wph + fo);
                bf16x8 Bl = *(const bf16x8*)(Wpl + fo);
#pragma unroll
                for (int mi = 0; mi < 2; ++mi) {
                    acc[mi][nj] = __builtin_amdgcn_mfma_f32_16x16x32_bf16(Ah[mi], Bh, acc[mi][nj], 0, 0, 0);
                    acc[mi][nj] = __builtin_amdgcn_mfma_f32_16x16x32_bf16(Ah[mi], Bl, acc[mi][nj], 0, 0, 0);
                    acc[mi][nj] = __builtin_amdgcn_mfma_f32_16x16x32_bf16(Al[mi], Bh, acc[mi][nj], 0, 0, 0);
                }
            }
        }
    }

    // epilogue: red[row] += y^2 ; C layout: row = mi*16 + kgrp*4 + q, col = jng*16 + lrow
#pragma unroll
    for (int mi = 0; mi < 2; ++mi) {
#pragma unroll
        for (int q = 0; q < 4; ++q) {
            float s = 0.0f;
#pragma unroll
            for (int nj = 0; nj < 8; ++nj) s = fmaf(acc[mi][nj][q], acc[mi][nj][q], s);
            s += __shfl_xor(s, 1);
            s += __shfl_xor(s, 2);
            s += __shfl_xor(s, 4);
            s += __shfl_xor(s, 8);
            if (lrow == 0) atomicAdd(&red_l[mi * 16 + kgrp * 4 + q], s);
        }
    }
    __syncthreads();
    if (tid < 32) {
        int b = slab * 32 + tid;
        if (b < Bq) out[b] = sqrtf(fmaxf(pv - red_l[tid], 1e-6f));
    }
}

extern "C" void kernel_launch(void* const* d_in, const int* in_sizes, int n_in,
                              void* d_out, int out_size, void* d_ws, size_t ws_size,
                              hipStream_t stream) {
    const float* x_star  = (const float*)d_in[0];
    const float* log_ls  = (const float*)d_in[1];
    const float* log_var = (const float*)d_in[2];
    const float* Z_raw   = (const float*)d_in[3];
    float* out = (float*)d_out;
    int Bq = in_sizes[0] / 5;

    char* ws = (char*)d_ws;
    double* Kd   = (double*)(ws + OFF_K);
    float*  Wf   = (float*)(ws + OFF_WF);
    double* Wd11 = (double*)(ws + OFF_W11);
    float*  pf   = (float*)(ws + OFF_PF);
    float*  Zst  = (float*)(ws + OFF_ZT);
    short*  Wph  = (short*)(ws + OFF_WPH);
    short*  Wpl  = (short*)(ws + OFF_WPL);

    k_build<<<4096, 256, 0, stream>>>(log_ls, log_var, Z_raw, Kd, pf, Zst);

    for (int kb = 0; kb < NBK; ++kb) {
        kw_diag<<<1, 512, 0, stream>>>(Kd, Wd11, Wf, kb);
        int R = M_N - (kb + 1) * BS;
        if (R > 0) {
            int nt = R / 64;
            kw_panel<<<nt, 256, 0, stream>>>(Kd, Wd11, kb);
            kw_update<<<nt * (nt + 1) / 2, 256, 0, stream>>>(Kd, kb);
        }
    }
    kw_trtri<<<dim3(4, 7), 512, 0, stream>>>(Kd, Wf);
    kw_pack<<<512, 256, 0, stream>>>(Wf, Wph, Wpl);

    int slabs = (Bq + 31) / 32;
    k_mm<<<slabs, 512, 0, stream>>>(x_star, pf, Zst, Wph, Wpl, out, Bq);
}

// Round 7
// 3554.882 us; speedup vs baseline: 1.9538x; 1.0485x over previous
//
#include <hip/hip_runtime.h>
#include <math.h>

// Sizes fixed by the problem.
#define B_TOT 131072
#define M_N   1024
#define BS    128      // Cholesky block size
#define NBK   8        // M_N / BS

typedef float    f32x4 __attribute__((ext_vector_type(4)));
typedef _Float16 f16x8 __attribute__((ext_vector_type(8)));

// Workspace layout (bytes). Total ~17.1 MB.
enum : size_t {
    OFF_KF  = 0,                          // fp32 K (Schur-updated)  4 MB
    OFF_LF  = (size_t)4 << 20,            // fp32 L off-diag strips  4 MB
    OFF_WF  = (size_t)8 << 20,            // fp32 W = L^-1 (lower)   4 MB
    OFF_WPH = (size_t)12 << 20,           // fp16 W packed hi        2 MB
    OFF_WPL = (size_t)14 << 20,           // fp16 W packed lo        2 MB
    OFF_RED = (size_t)16 << 20,           // f32 redp[2][B]          1 MB
    OFF_PF  = (size_t)17 << 20,           // fp32 params (6)
    OFF_ZT  = ((size_t)17 << 20) + 256,   // fp32 Zs_t [5][1024]     20 KB
};

__device__ __constant__ float c_zscale[5] = {0.15f, 0.1f, 0.05f, 800.0f, 20.0f};
__device__ __constant__ float c_zshift[5] = {0.0f, 0.0f, 0.0f, 600.0f, 5.0f};

// ---------------- fused: params + Zst + K = matern52 + jitter (fp32) ----------------
// grid 4096: block b covers K row i = b>>2, cols (b&3)*256 + tid.
__global__ __launch_bounds__(256) void k_build(const float* __restrict__ log_ls,
                                               const float* __restrict__ log_var,
                                               const float* __restrict__ Zraw,
                                               float* __restrict__ Kf,
                                               float* __restrict__ pf,
                                               float* __restrict__ Zst) {
    __shared__ float ps[6];
    __shared__ float zsi[5];
    int tid = threadIdx.x;
    if (tid < 5) ps[tid] = 1.0f / (__expf(log_ls[tid]) + 1e-8f);
    if (tid == 5) ps[5] = __expf(log_var[0]);
    __syncthreads();
    int i = blockIdx.x >> 2;
    int j = (blockIdx.x & 3) * 256 + tid;
    if (tid < 5) zsi[tid] = (Zraw[i * 5 + tid] * c_zscale[tid] + c_zshift[tid]) * ps[tid];
    __syncthreads();
    float d2 = 0.0f;
#pragma unroll
    for (int d = 0; d < 5; ++d) {
        float zj = (Zraw[j * 5 + d] * c_zscale[d] + c_zshift[d]) * ps[d];
        float df = zsi[d] - zj;
        d2 += df * df;
    }
    float dd = d2 + 1e-8f;
    float dist = sqrtf(dd);
    float s = 2.23606798f * dist;
    float v = ps[5] * (1.0f + s + 1.66666667f * dd) * __expf(-s);
    if (i == j) v += 1e-4f;
    Kf[(size_t)i * M_N + j] = v;
    if (blockIdx.x < 4) {               // Zst side output
        int m = blockIdx.x * 256 + tid;
#pragma unroll
        for (int d = 0; d < 5; ++d)
            Zst[d * M_N + m] = (Zraw[m * 5 + d] * c_zscale[d] + c_zshift[d]) * ps[d];
    }
    if (blockIdx.x == 4 && tid < 6) pf[tid] = ps[tid];
}

// ---------------- Cholesky diag block (fp32, 512 thr) + W11 = inv(L11) ----------------
__global__ __launch_bounds__(512) void kw_diag(float* __restrict__ Kf,
                                               float* __restrict__ Wf, int kb) {
    __shared__ float As[128][129];    // lower: A/L ; upper [c][r] (r>c): X = inv(L)
    __shared__ float sinv[128];
    int tid = threadIdx.x;
    int r0 = kb * BS;
    for (int idx = tid; idx < BS * BS; idx += 512) {
        int rr = idx >> 7, cc = idx & 127;
        As[rr][cc] = Kf[(size_t)(r0 + rr) * M_N + r0 + cc];
    }
    __syncthreads();

    int r = tid & 127, q = tid >> 7;
    for (int p = 0; p < 16; ++p) {
        int j0 = p * 8;
        for (int j = j0; j < j0 + 8; ++j) {
            if (tid == j) {
                float d = sqrtf(As[j][j]);
                As[j][j] = d;
                sinv[j] = 1.0f / d;
            }
            __syncthreads();
            float arj = 0.0f;
            if (q == 0 && r > j) {
                arj = As[r][j] * sinv[j];
                As[r][j] = arj;
            }
            __syncthreads();
            if (q == 0 && r > j) {
#pragma unroll
                for (int c = j + 1; c < j0 + 8; ++c)
                    As[r][c] -= arj * As[c][j];     // As[c][j]: broadcast
            }
        }
        __syncthreads();
        // rank-8 trailing update, 4-way split over quarters
        if (p < 15) {
            float a[8];
#pragma unroll
            for (int t = 0; t < 8; ++t) a[t] = As[r][j0 + t];
            for (int c = j0 + 8 + q; c < 128; c += 4) {
                if (r >= c) {
                    float s = As[r][c];
#pragma unroll
                    for (int t = 0; t < 8; ++t) s -= a[t] * As[c][j0 + t];
                    As[r][c] = s;
                }
            }
        }
        __syncthreads();
    }

    // W11 = inv(L11): thread c (<128) owns column c; X[t][c] stored at As[c][t] (t>c)
    if (tid < 128) {
        int c = tid;
        for (int rb = 0; rb < 16; ++rb) {
            int r0b = rb * 8;
            if (c >= r0b + 8) continue;
            float s[8];
#pragma unroll
            for (int i = 0; i < 8; ++i) s[i] = 0.0f;
            for (int t = 0; t < r0b; ++t) {
                if (t >= c) {
                    float xt = (t == c) ? sinv[c] : As[c][t];
#pragma unroll
                    for (int i = 0; i < 8; ++i) s[i] += As[r0b + i][t] * xt;
                }
            }
            float xloc[8];
#pragma unroll
            for (int i = 0; i < 8; ++i) {
                int rr = r0b + i;
                float v = 0.0f;
                if (rr >= c) {
                    v = ((rr == c) ? 1.0f : 0.0f) - s[i];
#pragma unroll
                    for (int t2 = 0; t2 < i; ++t2) {
                        int tt = r0b + t2;
                        if (tt >= c) v -= As[rr][tt] * xloc[t2];
                    }
                    v *= sinv[rr];
                    if (rr > c) As[c][rr] = v;
                }
                xloc[i] = v;
            }
        }
    }
    __syncthreads();
    for (int idx = tid; idx < BS * BS; idx += 512) {
        int rr = idx >> 7, cc = idx & 127;
        if (rr >= cc)
            Wf[(size_t)(r0 + rr) * M_N + r0 + cc] = (rr == cc) ? sinv[rr] : As[cc][rr];
    }
}

// ---------------- strip: S(64x128) = A21[row0..] * W11^T (fp32, into LDS) ----------------
static __device__ void d_strip(const float* __restrict__ Kf, const float* __restrict__ Wf,
                               int cb, int row0, float (*S)[129],
                               float (*Ast)[17], float (*Wst)[128], int tid) {
    int c = tid & 127, q = tid >> 7;
    float acc[32];
#pragma unroll
    for (int i = 0; i < 32; ++i) acc[i] = 0.0f;
    for (int tc = 0; tc < 8; ++tc) {
        int tb = tc * 16;
        __syncthreads();
        for (int idx = tid; idx < 64 * 16; idx += 256) {
            int rr = idx >> 4, tt = idx & 15;
            Ast[rr][tt] = Kf[(size_t)(row0 + rr) * M_N + cb + tb + tt];
        }
        for (int idx = tid; idx < 128 * 16; idx += 256) {
            int cc = idx >> 4, tt = idx & 15;
            Wst[tt][cc] = (tb + tt <= cc) ? Wf[(size_t)(cb + cc) * M_N + cb + tb + tt] : 0.0f;
        }
        __syncthreads();
#pragma unroll
        for (int t = 0; t < 16; ++t) {
            float w = Wst[t][c];
#pragma unroll
            for (int i = 0; i < 32; ++i) acc[i] += Ast[q * 32 + i][t] * w;
        }
    }
#pragma unroll
    for (int i = 0; i < 32; ++i) S[q * 32 + i][c] = acc[i];
}

// ---------------- step: recompute strips, trailing update, L write (merged) ----------
__global__ __launch_bounds__(256) void kw_step(float* __restrict__ Kf,
                                               const float* __restrict__ Wf,
                                               float* __restrict__ Lf, int kb) {
    __shared__ float SA[64][129];
    __shared__ float SB[64][129];
    __shared__ float Ast[64][17];
    __shared__ float Wst[16][128];
    int tid = threadIdx.x;
    int v = blockIdx.x;
    int by = 0;
    while ((by + 1) * (by + 2) / 2 <= v) ++by;
    int bx = v - by * (by + 1) / 2;
    int base = (kb + 1) * BS;
    int cb = kb * BS;
    int gr0 = base + by * 64, gc0 = base + bx * 64;

    d_strip(Kf, Wf, cb, gr0, SA, Ast, Wst, tid);
    if (bx != by) d_strip(Kf, Wf, cb, gc0, SB, Ast, Wst, tid);
    float (*PB)[129] = (bx == by) ? SA : SB;
    __syncthreads();

    // A22 tile -= SA * PB^T
    int tx = tid & 15, ty = tid >> 4;
    float acc[4][4];
#pragma unroll
    for (int i = 0; i < 4; ++i)
#pragma unroll
        for (int j = 0; j < 4; ++j) acc[i][j] = 0.0f;
    for (int t = 0; t < 128; ++t) {
        float a[4], b[4];
#pragma unroll
        for (int i = 0; i < 4; ++i) a[i] = SA[ty * 4 + i][t];
#pragma unroll
        for (int j = 0; j < 4; ++j) b[j] = PB[tx * 4 + j][t];
#pragma unroll
        for (int i = 0; i < 4; ++i)
#pragma unroll
            for (int j = 0; j < 4; ++j) acc[i][j] = fmaf(a[i], b[j], acc[i][j]);
    }
#pragma unroll
    for (int i = 0; i < 4; ++i)
#pragma unroll
        for (int j = 0; j < 4; ++j)
            Kf[(size_t)(gr0 + ty * 4 + i) * M_N + gc0 + tx * 4 + j] -= acc[i][j];

    // diagonal tiles persist the L21 strip
    if (by == bx) {
        for (int idx = tid; idx < 64 * 128; idx += 256)
            Lf[(size_t)(gr0 + (idx >> 7)) * M_N + cb + (idx & 127)] = SA[idx >> 7][idx & 127];
    }
}

// ---------------- trtri: single launch, fp32, per (col-block j, 32-col tile) ----------
__global__ __launch_bounds__(512) void kw_trtri(const float* __restrict__ Lf,
                                                float* __restrict__ Wf) {
    __shared__ float Ls[128][33];            // L / W_ii K-chunk
    __shared__ float Ws[32][33];             // W_jj K-chunk (t == j)
    __shared__ float Whist[6][128][33];      // this block's W_t tiles, t-j-1
    __shared__ float Ps[128][33];            // P tile
    int j  = blockIdx.y;                     // 0..6
    int ct = blockIdx.x;                     // 0..3
    int c0 = j * BS + ct * 32;
    int tid = threadIdx.x;
    int rq = tid >> 2, cq = tid & 3;         // row rq, cols cq*8..cq*8+7

    for (int i = j + 1; i < 8; ++i) {
        float acc[8];
#pragma unroll
        for (int c = 0; c < 8; ++c) acc[c] = 0.0f;
        for (int t = j; t < i; ++t) {
            for (int ch = 0; ch < 4; ++ch) {
                int tb = t * BS + ch * 32;
                __syncthreads();
                for (int idx = tid; idx < 128 * 32; idx += 512) {
                    int rr = idx >> 5, tt = idx & 31;
                    Ls[rr][tt] = Lf[(size_t)(i * BS + rr) * M_N + tb + tt];
                }
                if (t == j) {
                    for (int idx = tid; idx < 32 * 32; idx += 512) {
                        int tt = idx >> 5, cc = idx & 31;
                        int gr = tb + tt, gc = c0 + cc;
                        Ws[tt][cc] = (gr >= gc) ? Wf[(size_t)gr * M_N + gc] : 0.0f;
                    }
                }
                __syncthreads();
                if (t == j) {
#pragma unroll
                    for (int tt = 0; tt < 32; ++tt) {
                        float l = Ls[rq][tt];
#pragma unroll
                        for (int c = 0; c < 8; ++c)
                            acc[c] = fmaf(l, Ws[tt][cq * 8 + c], acc[c]);
                    }
                } else {
                    const float (*Wh)[33] = Whist[t - j - 1];
#pragma unroll
                    for (int tt = 0; tt < 32; ++tt) {
                        float l = Ls[rq][tt];
#pragma unroll
                        for (int c = 0; c < 8; ++c)
                            acc[c] = fmaf(l, Wh[ch * 32 + tt][cq * 8 + c], acc[c]);
                    }
                }
            }
        }
        __syncthreads();
#pragma unroll
        for (int c = 0; c < 8; ++c) Ps[rq][cq * 8 + c] = acc[c];
        float a2[8];
#pragma unroll
        for (int c = 0; c < 8; ++c) a2[c] = 0.0f;
        for (int ch = 0; ch < 4; ++ch) {
            __syncthreads();
            for (int idx = tid; idx < 128 * 32; idx += 512) {
                int rr = idx >> 5, tt = idx & 31;
                Ls[rr][tt] = (rr >= ch * 32 + tt)
                           ? Wf[(size_t)(i * BS + rr) * M_N + i * BS + ch * 32 + tt] : 0.0f;
            }
            __syncthreads();
#pragma unroll
            for (int tt = 0; tt < 32; ++tt) {
                float l = Ls[rq][tt];
#pragma unroll
                for (int c = 0; c < 8; ++c)
                    a2[c] = fmaf(l, Ps[ch * 32 + tt][cq * 8 + c], a2[c]);
            }
        }
        __syncthreads();
#pragma unroll
        for (int c = 0; c < 8; ++c) {
            float v = -a2[c];
            Wf[(size_t)(i * BS + rq) * M_N + c0 + cq * 8 + c] = v;
            if (i < 7) Whist[i - j - 1][rq][cq * 8 + c] = v;
        }
        __syncthreads();
    }
}

// ---------------- pack W (fp32) into MFMA B-fragment order, fp16 hi/lo ----------------
__global__ void kw_pack(const float* __restrict__ Wf, _Float16* __restrict__ Wph,
                        _Float16* __restrict__ Wpl) {
    int T = blockIdx.x * 256 + threadIdx.x;
    int lane = T & 63, fid = T >> 6;
    int jn = fid & 63, kik = fid >> 6;
    int ki = kik & 3, kc = kik >> 2;
    int j  = jn * 16 + (lane & 15);
    int kb = kc * 128 + ki * 32 + (lane >> 4) * 8;
    f16x8 h, lo;
#pragma unroll
    for (int e = 0; e < 8; ++e) {
        int k = kb + e;
        float v = (k <= j) ? Wf[(size_t)j * M_N + k] : 0.0f;
        _Float16 hh = (_Float16)v;
        h[e]  = hh;
        lo[e] = (_Float16)(v - (float)hh);
    }
    size_t off = (size_t)fid * 512 + lane * 8;
    *(f16x8*)(Wph + off) = h;
    *(f16x8*)(Wpl + off) = lo;
}

// ---------------- main MFMA kernel: 32 rows x 512 cols (2 col-panels), fp16 ----------
__global__ __launch_bounds__(256) void k_mm(const float* __restrict__ x_star,
                                            const float* __restrict__ pf,
                                            const float* __restrict__ Zst,
                                            const _Float16* __restrict__ Wph,
                                            const _Float16* __restrict__ Wpl,
                                            float* __restrict__ redp, int Bq) {
    __shared__ __align__(16) char kls[32 * 256];   // fp16 k-tile [row][128*2B], swizzled
    __shared__ float red_l[32];
    int tid  = threadIdx.x;
    int slab = blockIdx.x, pp = blockIdx.y;
    int w = tid >> 6, lane = tid & 63;
    int lrow = lane & 15, kgrp = lane >> 4;

    // staging identity: row srow, 16 cols at sg*16
    int srow = tid >> 3, sg = tid & 7;
    int qrow = slab * 32 + srow;
    int qc = (qrow < Bq) ? qrow : (Bq - 1);
    float xv0 = x_star[(size_t)qc * 5 + 0] * pf[0];
    float xv1 = x_star[(size_t)qc * 5 + 1] * pf[1];
    float xv2 = x_star[(size_t)qc * 5 + 2] * pf[2];
    float xv3 = x_star[(size_t)qc * 5 + 3] * pf[3];
    float xv4 = x_star[(size_t)qc * 5 + 4] * pf[4];
    float pv = pf[5];
    if (tid < 32) red_l[tid] = 0.0f;

    f32x4 acc[2][8];
#pragma unroll
    for (int mi = 0; mi < 2; ++mi)
#pragma unroll
        for (int nj = 0; nj < 8; ++nj) acc[mi][nj] = (f32x4)(0.0f);

    int jmax_w = (pp * 32 + 28 + ((w + 3) & 3)) * 16 + 15;   // wave max col
    int KC = pp ? 8 : 4;

    for (int kc = 0; kc < KC; ++kc) {
        // ---- compute 16 k values (fp16), 2 batches of 8 ----
        f16x8 hv[2];
#pragma unroll
        for (int b = 0; b < 2; ++b) {
            int lb = kc * 128 + sg * 16 + b * 8;
            float z0[8], z1[8], z2[8], z3[8], z4[8];
            *(float4*)&z0[0] = *(const float4*)&Zst[lb];
            *(float4*)&z0[4] = *(const float4*)&Zst[lb + 4];
            *(float4*)&z1[0] = *(const float4*)&Zst[M_N + lb];
            *(float4*)&z1[4] = *(const float4*)&Zst[M_N + lb + 4];
            *(float4*)&z2[0] = *(const float4*)&Zst[2 * M_N + lb];
            *(float4*)&z2[4] = *(const float4*)&Zst[2 * M_N + lb + 4];
            *(float4*)&z3[0] = *(const float4*)&Zst[3 * M_N + lb];
            *(float4*)&z3[4] = *(const float4*)&Zst[3 * M_N + lb + 4];
            *(float4*)&z4[0] = *(const float4*)&Zst[4 * M_N + lb];
            *(float4*)&z4[4] = *(const float4*)&Zst[4 * M_N + lb + 4];
#pragma unroll
            for (int e = 0; e < 8; ++e) {
                float dx0 = xv0 - z0[e], dx1 = xv1 - z1[e], dx2 = xv2 - z2[e],
                      dx3 = xv3 - z3[e], dx4 = xv4 - z4[e];
                float d2 = dx0 * dx0 + dx1 * dx1 + dx2 * dx2 + dx3 * dx3 + dx4 * dx4;
                float ddv = d2 + 1e-8f;
                float dist = sqrtf(ddv);
                float sv = 2.23606798f * dist;
                hv[b][e] = (_Float16)(pv * (1.0f + sv + 1.66666667f * ddv) * __expf(-sv));
            }
        }
        __syncthreads();                  // prior-chunk MFMA reads done
        {
            int o0 = srow * 256 + ((sg * 32) ^ ((srow & 15) << 4));
            int o1 = srow * 256 + ((sg * 32 + 16) ^ ((srow & 15) << 4));
            *(f16x8*)(&kls[o0]) = hv[0];
            *(f16x8*)(&kls[o1]) = hv[1];
        }
        __syncthreads();                  // chunk visible

        // ---- MFMA over this K chunk ----
        for (int ki = 0; ki < 4; ++ki) {
            int kmin = kc * 128 + ki * 32;
            if (kmin > jmax_w) break;            // wave-uniform
            f16x8 A_[2];
#pragma unroll
            for (int mi = 0; mi < 2; ++mi) {
                int row = mi * 16 + lrow;
                int cb  = ki * 64 + kgrp * 16;
                A_[mi] = *(const f16x8*)(&kls[row * 256 + (cb ^ ((row & 15) << 4))]);
            }
#pragma unroll
            for (int nj = 0; nj < 8; ++nj) {
                int jng = pp * 32 + nj * 4 + ((w + nj) & 3);   // balanced interleave
                if (kmin > jng * 16 + 15) continue;            // all-zero W fragment
                size_t fo = ((size_t)((kc * 4 + ki) * 64 + jng)) * 512 + lane * 8;
                f16x8 Bh = *(const f16x8*)(Wph + fo);
                f16x8 Bl = *(const f16x8*)(Wpl + fo);
#pragma unroll
                for (int mi = 0; mi < 2; ++mi) {
                    acc[mi][nj] = __builtin_amdgcn_mfma_f32_16x16x32_f16(A_[mi], Bh, acc[mi][nj], 0, 0, 0);
                    acc[mi][nj] = __builtin_amdgcn_mfma_f32_16x16x32_f16(A_[mi], Bl, acc[mi][nj], 0, 0, 0);
                }
            }
        }
    }

    // epilogue: red[row] += y^2 ; C layout: row = mi*16 + kgrp*4 + q, col = jng*16 + lrow
#pragma unroll
    for (int mi = 0; mi < 2; ++mi) {
#pragma unroll
        for (int q = 0; q < 4; ++q) {
            float s = 0.0f;
#pragma unroll
            for (int nj = 0; nj < 8; ++nj) s = fmaf(acc[mi][nj][q], acc[mi][nj][q], s);
            s += __shfl_xor(s, 1);
            s += __shfl_xor(s, 2);
            s += __shfl_xor(s, 4);
            s += __shfl_xor(s, 8);
            if (lrow == 0) atomicAdd(&red_l[mi * 16 + kgrp * 4 + q], s);
        }
    }
    __syncthreads();
    if (tid < 32) {
        int b = slab * 32 + tid;
        if (b < Bq) redp[(size_t)pp * Bq + b] = red_l[tid];
    }
}

// ---------------- final combine ----------------
__global__ void k_fin(const float* __restrict__ redp, const float* __restrict__ pf,
                      float* __restrict__ out, int Bq) {
    int b = blockIdx.x * 256 + threadIdx.x;
    if (b < Bq) {
        float red = redp[b] + redp[(size_t)Bq + b];
        out[b] = sqrtf(fmaxf(pf[5] - red, 1e-6f));
    }
}

extern "C" void kernel_launch(void* const* d_in, const int* in_sizes, int n_in,
                              void* d_out, int out_size, void* d_ws, size_t ws_size,
                              hipStream_t stream) {
    const float* x_star  = (const float*)d_in[0];
    const float* log_ls  = (const float*)d_in[1];
    const float* log_var = (const float*)d_in[2];
    const float* Z_raw   = (const float*)d_in[3];
    float* out = (float*)d_out;
    int Bq = in_sizes[0] / 5;

    char* ws = (char*)d_ws;
    float*     Kf   = (float*)(ws + OFF_KF);
    float*     Lf   = (float*)(ws + OFF_LF);
    float*     Wf   = (float*)(ws + OFF_WF);
    _Float16*  Wph  = (_Float16*)(ws + OFF_WPH);
    _Float16*  Wpl  = (_Float16*)(ws + OFF_WPL);
    float*     redp = (float*)(ws + OFF_RED);
    float*     pf   = (float*)(ws + OFF_PF);
    float*     Zst  = (float*)(ws + OFF_ZT);

    k_build<<<4096, 256, 0, stream>>>(log_ls, log_var, Z_raw, Kf, pf, Zst);

    for (int kb = 0; kb < NBK; ++kb) {
        kw_diag<<<1, 512, 0, stream>>>(Kf, Wf, kb);
        int R = M_N - (kb + 1) * BS;
        if (R > 0) {
            int nt = R / 64;
            kw_step<<<nt * (nt + 1) / 2, 256, 0, stream>>>(Kf, Wf, Lf, kb);
        }
    }
    kw_trtri<<<dim3(4, 7), 512, 0, stream>>>(Lf, Wf);
    kw_pack<<<512, 256, 0, stream>>>(Wf, Wph, Wpl);

    int slabs = (Bq + 31) / 32;
    k_mm<<<dim3(slabs, 2), 256, 0, stream>>>(x_star, pf, Zst, Wph, Wpl, redp, Bq);
    k_fin<<<(Bq + 255) / 256, 256, 0, stream>>>(redp, pf, out, Bq);
}